// Round 1
// baseline (1310.306 us; speedup 1.0000x reference)
//
#include <hip/hip_runtime.h>
#include <hip/hip_bf16.h>
#include <math.h>

// Problem constants (B, DIM, HEADS, WS, H, W) = (8, 192, 6, 8, 128, 128)
constexpr int BB = 8, CCH = 192, IH = 128, IW = 128;
constexpr int WSZ = 8;                    // window size
constexpr int NWIN = 256;                 // 16x16 windows per image
constexpr int NH = 6, HDIM = 32, NPRED = 48;
constexpr int NPIX = IH * IW;             // 16384
constexpr int TOPK = 13107;               // int(0.8*128*128)

__device__ __forceinline__ float toF(float v) { return v; }
__device__ __forceinline__ float toF(__hip_bfloat16 v) { return __bfloat162float(v); }

template <typename T> __device__ __forceinline__ T fromF(float v);
template <> __device__ __forceinline__ float fromF<float>(float v) { return v; }
template <> __device__ __forceinline__ __hip_bfloat16 fromF<__hip_bfloat16>(float v) { return __float2bfloat16(v); }

__device__ __forceinline__ unsigned monot(float f) {
    unsigned u = __float_as_uint(f);
    return (u & 0x80000000u) ? ~u : (u | 0x80000000u);
}

// ---------------------------------------------------------------------------
// K1: per (b,c) row: exact top-k threshold on var (stable ties like lax.top_k),
//     then masked 8x8 avg-pool + leaky_relu -> pooled (b, c, 16, 16)
// ---------------------------------------------------------------------------
__global__ __launch_bounds__(256) void k1_pool(const float* __restrict__ x,
                                               const float* __restrict__ var,
                                               float* __restrict__ pooled) {
    int row = blockIdx.x;                     // b*CCH + c
    const float* vrow = var + (size_t)row * NPIX;
    const float* xrow = x + (size_t)row * NPIX;
    int tid = threadIdx.x;

    __shared__ unsigned hist[256];
    __shared__ unsigned s_prefix, s_remaining;
    __shared__ unsigned eq_idx[256];
    __shared__ unsigned eq_cnt;

    unsigned prefix = 0;
    unsigned remaining = TOPK;
    for (int pass = 0; pass < 4; ++pass) {
        int shift = 24 - 8 * pass;
        hist[tid] = 0;
        __syncthreads();
        for (int i = tid; i < NPIX; i += 256) {
            unsigned m = monot(vrow[i]);
            bool ok = (pass == 0) || ((m >> (shift + 8)) == prefix);
            if (ok) atomicAdd(&hist[(m >> shift) & 255u], 1u);
        }
        __syncthreads();
        if (tid == 0) {
            unsigned cum = 0; int bs = 255;
            for (; bs >= 0; --bs) {
                if (cum + hist[bs] >= remaining) break;
                cum += hist[bs];
            }
            s_prefix = (prefix << 8) | (unsigned)bs;
            s_remaining = remaining - cum;
        }
        __syncthreads();
        prefix = s_prefix;
        remaining = s_remaining;
        __syncthreads();
    }
    unsigned thr = prefix;
    unsigned need_eq = remaining;   // # of equal-valued elems to include (lowest index first)

    if (tid == 0) eq_cnt = 0;
    __syncthreads();
    for (int i = tid; i < NPIX; i += 256) {
        if (monot(vrow[i]) == thr) {
            unsigned pos = atomicAdd(&eq_cnt, 1u);
            if (pos < 256) eq_idx[pos] = (unsigned)i;
        }
    }
    __syncthreads();
    int ecnt = (int)min(eq_cnt, 256u);
    if (tid == 0) {
        for (int a = 1; a < ecnt; ++a) {        // insertion sort (tiny)
            unsigned key = eq_idx[a]; int q = a - 1;
            while (q >= 0 && eq_idx[q] > key) { eq_idx[q + 1] = eq_idx[q]; --q; }
            eq_idx[q + 1] = key;
        }
    }
    __syncthreads();

    // pooled: thread = window
    int wy = tid >> 4, wx = tid & 15;
    float s = 0.f;
    for (int dy = 0; dy < WSZ; ++dy) {
        int y = wy * WSZ + dy;
        for (int dx = 0; dx < WSZ; ++dx) {
            int xg = wx * WSZ + dx;
            int i = y * IW + xg;
            unsigned m = monot(vrow[i]);
            float mult;
            if (m > thr) mult = 1.0f;
            else if (m < thr) mult = 0.6f;
            else {
                unsigned rank = 0;
                for (int e = 0; e < ecnt; ++e) if (eq_idx[e] < (unsigned)i) ++rank;
                mult = (rank < need_eq) ? 1.0f : 0.6f;
            }
            s += xrow[i] * mult;
        }
    }
    s *= (1.0f / 64.0f);
    float pv = s > 0.f ? s : 0.01f * s;       // leaky_relu(0.01)
    pooled[(size_t)row * NWIN + tid] = pv;
}

// ---------------------------------------------------------------------------
// K2: per (b, window): dots with bias_w/scale_w -> sb[p][win] = {sx, sy, bx/16, by/16}
// ---------------------------------------------------------------------------
__global__ __launch_bounds__(64) void k2_sb(const float* __restrict__ pooled,
                                            const float* __restrict__ bias_w,
                                            const float* __restrict__ bias_b,
                                            const float* __restrict__ scale_w,
                                            const float* __restrict__ scale_b,
                                            float* __restrict__ sb) {
    int blk = blockIdx.x;
    int b = blk / NWIN, w = blk % NWIN;
    int tid = threadIdx.x;
    __shared__ float pcol[CCH];
    __shared__ float res[24];
    for (int c = tid; c < CCH; c += 64) pcol[c] = pooled[(size_t)(b * CCH + c) * NWIN + w];
    __syncthreads();
    if (tid < 24) {
        bool isScale = tid >= 12;
        int o = isScale ? tid - 12 : tid;
        const float* Wt = isScale ? scale_w : bias_w;
        float acc = 0.f;
        for (int c = 0; c < CCH; ++c) acc += Wt[o * CCH + c] * pcol[c];
        acc += (isScale ? scale_b[o] : bias_b[o]);
        if (!isScale) acc *= (1.0f / 16.0f);   // biases / (w//WS == h//WS == 16)
        res[tid] = acc;
    }
    __syncthreads();
    if (tid < NH) {
        int p = b * NH + tid;
        float4 v;
        v.x = res[12 + 2 * tid];       // sx
        v.y = res[12 + 2 * tid + 1];   // sy
        v.z = res[2 * tid];            // bx (already /16)
        v.w = res[2 * tid + 1];        // by
        ((float4*)sb)[(size_t)p * NWIN + w] = v;
    }
}

// ---------------------------------------------------------------------------
// K3: qkv 1x1 conv as tiled GEMM. out ch o in [0,576): t=o/192 -> q/k/v,
//     layout (b, 192, 128*128) each.
// ---------------------------------------------------------------------------
template <typename T>
__global__ __launch_bounds__(256) void k3_qkv(const float* __restrict__ x,
                                              const float* __restrict__ qkv_w,
                                              const float* __restrict__ qkv_b,
                                              T* __restrict__ qb, T* __restrict__ kb, T* __restrict__ vb) {
    int b = blockIdx.z;
    int o0 = blockIdx.y * 64;
    int px0 = blockIdx.x * 64;
    int tid = threadIdx.x;
    __shared__ float Xs[32][64];
    __shared__ float Wt[32][65];
    float acc[4][4] = {};
    int to = tid >> 4, tp = tid & 15;

    for (int c0 = 0; c0 < CCH; c0 += 32) {
        {
            int cc = tid >> 6;            // 0..3
            int px = tid & 63;
#pragma unroll
            for (int r = 0; r < 8; ++r)
                Xs[cc + r * 4][px] = x[(size_t)(b * CCH + c0 + cc + r * 4) * NPIX + px0 + px];
            int oo = tid >> 5;            // 0..7
            int c2 = tid & 31;
#pragma unroll
            for (int r = 0; r < 8; ++r)
                Wt[c2][oo + r * 8] = qkv_w[(size_t)(o0 + oo + r * 8) * CCH + c0 + c2];
        }
        __syncthreads();
#pragma unroll
        for (int cc = 0; cc < 32; ++cc) {
            float xv[4], wv[4];
#pragma unroll
            for (int j = 0; j < 4; ++j) xv[j] = Xs[cc][tp * 4 + j];
#pragma unroll
            for (int i = 0; i < 4; ++i) wv[i] = Wt[cc][to * 4 + i];
#pragma unroll
            for (int i = 0; i < 4; ++i)
#pragma unroll
                for (int j = 0; j < 4; ++j) acc[i][j] += wv[i] * xv[j];
        }
        __syncthreads();
    }
#pragma unroll
    for (int i = 0; i < 4; ++i) {
        int o = o0 + to * 4 + i;
        float bias = qkv_b[o];
        int t = o / CCH;
        int ch = o % CCH;
        T* dst = (t == 0) ? qb : (t == 1) ? kb : vb;
        size_t base = (size_t)(b * CCH + ch) * NPIX + px0 + tp * 4;
#pragma unroll
        for (int j = 0; j < 4; ++j) dst[base + j] = fromF<T>(acc[i][j] + bias);
    }
}

// ---------------------------------------------------------------------------
// K4: per (b, head, window): bilinear-sample k,v at predicted grid, windowed
//     attention with relative bias, write att output in (b,c,h,w) layout.
// ---------------------------------------------------------------------------
template <typename T>
__global__ __launch_bounds__(256) void k4_attn(const T* __restrict__ qb,
                                               const T* __restrict__ kb,
                                               const T* __restrict__ vb,
                                               const float* __restrict__ sb,
                                               const float* __restrict__ rel_table,
                                               float* __restrict__ att) {
    int win = blockIdx.x, head = blockIdx.y, b = blockIdx.z;
    int wy = win >> 4, wx = win & 15;
    int p = b * NH + head;
    int tid = threadIdx.x;

    __shared__ float qw[64][33];
    __shared__ float kw[64][33];
    __shared__ float vw[64][33];
    __shared__ float S[64][65];

    // load q tile: thread (d = tid/8, dy = tid%8) loads 8 x's
    {
        int d = tid >> 3, dy = tid & 7;
        const T* qrow = qb + ((size_t)(p * HDIM + d) * IH + wy * WSZ + dy) * IW + wx * WSZ;
#pragma unroll
        for (int dx = 0; dx < 8; ++dx) qw[dy * 8 + dx][d] = toF(qrow[dx]);
    }

    // sampling: thread (j = tid/4, qq = tid%4) handles 8 channels of pixel j
    {
        float4 sbv = ((const float4*)sb)[(size_t)p * NWIN + win];
        int j = tid >> 2, qq = tid & 3;
        int dy = j >> 3, dx = j & 7;
        int yg = wy * WSZ + dy, xg = wx * WSZ + dx;
        float gx = -1.0f + xg * (2.0f / 127.0f) + ((float)dx - 3.5f) * (2.0f / 127.0f) * sbv.x + sbv.z;
        float gy = -1.0f + yg * (2.0f / 127.0f) + ((float)dy - 3.5f) * (2.0f / 127.0f) * sbv.y + sbv.w;
        float fx = (gx + 1.0f) * 0.5f * 127.0f;
        float fy = (gy + 1.0f) * 0.5f * 127.0f;
        float x0f = floorf(fx), y0f = floorf(fy);
        float wx1 = fx - x0f, wy1 = fy - y0f;
        int ix0 = (int)x0f, iy0 = (int)y0f;
        int ix1 = ix0 + 1, iy1 = iy0 + 1;
        float w00 = (1.0f - wx1) * (1.0f - wy1);
        float w10 = wx1 * (1.0f - wy1);
        float w01 = (1.0f - wx1) * wy1;
        float w11 = wx1 * wy1;
        bool vX0 = (ix0 >= 0) && (ix0 < IW), vX1 = (ix1 >= 0) && (ix1 < IW);
        bool vY0 = (iy0 >= 0) && (iy0 < IH), vY1 = (iy1 >= 0) && (iy1 < IH);
        if (!(vX0 && vY0)) w00 = 0.f;
        if (!(vX1 && vY0)) w10 = 0.f;
        if (!(vX0 && vY1)) w01 = 0.f;
        if (!(vX1 && vY1)) w11 = 0.f;
        int cx0 = min(max(ix0, 0), IW - 1), cx1 = min(max(ix1, 0), IW - 1);
        int cy0 = min(max(iy0, 0), IH - 1), cy1 = min(max(iy1, 0), IH - 1);
        size_t o00 = (size_t)cy0 * IW + cx0, o10 = (size_t)cy0 * IW + cx1;
        size_t o01 = (size_t)cy1 * IW + cx0, o11 = (size_t)cy1 * IW + cx1;
        const T* kbase = kb + (size_t)(p * HDIM) * NPIX;
        const T* vbase = vb + (size_t)(p * HDIM) * NPIX;
        for (int c = qq * 8; c < qq * 8 + 8; ++c) {
            size_t coff = (size_t)c * NPIX;
            float kval = w00 * toF(kbase[coff + o00]) + w10 * toF(kbase[coff + o10]) +
                         w01 * toF(kbase[coff + o01]) + w11 * toF(kbase[coff + o11]);
            float vval = w00 * toF(vbase[coff + o00]) + w10 * toF(vbase[coff + o10]) +
                         w01 * toF(vbase[coff + o01]) + w11 * toF(vbase[coff + o11]);
            kw[j][c] = kval;
            vw[j][c] = vval;
        }
    }
    __syncthreads();

    // scores: thread (i = tid%64, j-block = (tid/64)*16)
    {
        int i = tid & 63;
        int jb0 = (tid >> 6) * 16;
        float qreg[32];
#pragma unroll
        for (int d = 0; d < 32; ++d) qreg[d] = qw[i][d];
        int cih = i >> 3, ciw = i & 7;
        for (int jj = 0; jj < 16; ++jj) {
            int j = jb0 + jj;
            float a = 0.f;
#pragma unroll
            for (int d = 0; d < 32; ++d) a += qreg[d] * kw[j][d];
            int cjh = j >> 3, cjw = j & 7;
            int ridx = (cih - cjh + 7) * 15 + (ciw - cjw + 7);
            S[i][j] = a * 0.17677669529663688f + rel_table[ridx * NH + head];
        }
    }
    __syncthreads();

    // softmax per row
    if (tid < 64) {
        float mx = -1e30f;
        for (int j = 0; j < 64; ++j) mx = fmaxf(mx, S[tid][j]);
        float sum = 0.f;
        for (int j = 0; j < 64; ++j) { float e = expf(S[tid][j] - mx); S[tid][j] = e; sum += e; }
        float inv = 1.0f / sum;
        for (int j = 0; j < 64; ++j) S[tid][j] *= inv;
    }
    __syncthreads();

    // PV: thread (i = tid/4, d-block = (tid%4)*8)
    {
        int i = tid >> 2;
        int d0 = (tid & 3) * 8;
        float acc[8] = {};
        for (int j = 0; j < 64; ++j) {
            float a = S[i][j];
#pragma unroll
            for (int dd = 0; dd < 8; ++dd) acc[dd] += a * vw[j][d0 + dd];
        }
        int dy = i >> 3, dx = i & 7;
        int yg = wy * WSZ + dy, xg = wx * WSZ + dx;
#pragma unroll
        for (int dd = 0; dd < 8; ++dd)
            att[((size_t)(b * CCH + head * HDIM + d0 + dd) * IH + yg) * IW + xg] = acc[dd];
    }
}

// ---------------------------------------------------------------------------
// K5: in-place projection on d_out. One block owns ALL 192 out channels of a
//     32-px tile (safe in-place), W staged in 32-wide c-chunks in LDS.
// ---------------------------------------------------------------------------
__global__ __launch_bounds__(256) void k5_proj(float* __restrict__ out,
                                               const float* __restrict__ proj_w,
                                               const float* __restrict__ proj_b) {
    int b = blockIdx.y;
    int px0 = blockIdx.x * 32;
    int tid = threadIdx.x;
    __shared__ float A[CCH][32];
    __shared__ float Wc[CCH][32];
    for (int idx = tid; idx < CCH * 32; idx += 256) {
        int c = idx >> 5, px = idx & 31;
        A[c][px] = out[(size_t)(b * CCH + c) * NPIX + px0 + px];
    }
    int px = tid & 31, og = tid >> 5;     // og 0..7 -> o = og*24 + i
    float acc[24];
#pragma unroll
    for (int i = 0; i < 24; ++i) acc[i] = proj_b[og * 24 + i];
    for (int c0 = 0; c0 < CCH; c0 += 32) {
        __syncthreads();
        for (int idx = tid; idx < CCH * 32; idx += 256) {
            int o = idx >> 5, cc = idx & 31;
            Wc[o][cc] = proj_w[(size_t)o * CCH + c0 + cc];
        }
        __syncthreads();
#pragma unroll 4
        for (int cc = 0; cc < 32; ++cc) {
            float a = A[c0 + cc][px];
#pragma unroll
            for (int i = 0; i < 24; ++i) acc[i] += Wc[og * 24 + i][cc] * a;
        }
    }
#pragma unroll
    for (int i = 0; i < 24; ++i)
        out[(size_t)(b * CCH + og * 24 + i) * NPIX + px0 + px] = acc[i];
}

// ---------------------------------------------------------------------------
extern "C" void kernel_launch(void* const* d_in, const int* in_sizes, int n_in,
                              void* d_out, int out_size, void* d_ws, size_t ws_size,
                              hipStream_t stream) {
    const float* x = (const float*)d_in[0];
    const float* var = (const float*)d_in[1];
    const float* qkv_w = (const float*)d_in[2];
    const float* qkv_b = (const float*)d_in[3];
    const float* bias_w = (const float*)d_in[4];
    const float* bias_b = (const float*)d_in[5];
    const float* scale_w = (const float*)d_in[6];
    const float* scale_b = (const float*)d_in[7];
    const float* proj_w = (const float*)d_in[8];
    const float* proj_b = (const float*)d_in[9];
    const float* rel_table = (const float*)d_in[10];
    float* out = (float*)d_out;

    char* ws = (char*)d_ws;
    float* pooled = (float*)ws;                         // 393216 floats
    float* sb = (float*)(ws + 393216ull * 4);           // 49152 floats
    char* qkv_base = ws + 1769472ull;
    const size_t elemQ = (size_t)BB * CCH * NPIX;       // 25165824 per tensor

    size_t need_f32 = 1769472ull + 3ull * elemQ * 4;
    size_t need_bf16 = 1769472ull + 3ull * elemQ * 2;
    if (ws_size < need_bf16) return;   // fail loudly (poison stays) -> tells us ws is tiny

    k1_pool<<<dim3(BB * CCH), dim3(256), 0, stream>>>(x, var, pooled);
    k2_sb<<<dim3(BB * NWIN), dim3(64), 0, stream>>>(pooled, bias_w, bias_b, scale_w, scale_b, sb);

    if (ws_size >= need_f32) {
        float* q = (float*)qkv_base;
        float* k = q + elemQ;
        float* v = k + elemQ;
        k3_qkv<float><<<dim3(NPIX / 64, 9, BB), dim3(256), 0, stream>>>(x, qkv_w, qkv_b, q, k, v);
        k4_attn<float><<<dim3(NWIN, NH, BB), dim3(256), 0, stream>>>(q, k, v, sb, rel_table, out);
    } else {
        __hip_bfloat16* q = (__hip_bfloat16*)qkv_base;
        __hip_bfloat16* k = q + elemQ;
        __hip_bfloat16* v = k + elemQ;
        k3_qkv<__hip_bfloat16><<<dim3(NPIX / 64, 9, BB), dim3(256), 0, stream>>>(x, qkv_w, qkv_b, q, k, v);
        k4_attn<__hip_bfloat16><<<dim3(NWIN, NH, BB), dim3(256), 0, stream>>>(q, k, v, sb, rel_table, out);
    }

    k5_proj<<<dim3(NPIX / 32, BB), dim3(256), 0, stream>>>(out, proj_w, proj_b);
}

// Round 2
// 761.501 us; speedup vs baseline: 1.7207x; 1.7207x over previous
//
#include <hip/hip_runtime.h>
#include <hip/hip_bf16.h>
#include <math.h>

constexpr int BB = 8, CCH = 192, IH = 128, IW = 128;
constexpr int WSZ = 8;
constexpr int NWIN = 256;
constexpr int NH = 6, HDIM = 32;
constexpr int NPIX = IH * IW;
constexpr int TOPK = 13107;

typedef __attribute__((ext_vector_type(8))) short bf16x8;
typedef __attribute__((ext_vector_type(4))) float f32x4;
typedef __attribute__((ext_vector_type(4))) unsigned short u16x4;
typedef __attribute__((ext_vector_type(8))) unsigned short u16x8;

__device__ __forceinline__ unsigned short f2bf(float f) {
    __hip_bfloat16 h = __float2bfloat16(f);
    return __builtin_bit_cast(unsigned short, h);
}
__device__ __forceinline__ float bf2f(unsigned short u) {
    return __uint_as_float((unsigned)u << 16);
}
__device__ __forceinline__ unsigned monot(float f) {
    unsigned u = __float_as_uint(f);
    return (u & 0x80000000u) ? ~u : (u | 0x80000000u);
}

// ---------------------------------------------------------------------------
// K1: per (b,c) row: exact top-k threshold on var (stable ties like lax.top_k),
//     then masked 8x8 avg-pool + leaky_relu -> pooled (b, c, 16, 16)
// ---------------------------------------------------------------------------
__global__ __launch_bounds__(256) void k1_pool(const float* __restrict__ x,
                                               const float* __restrict__ var,
                                               float* __restrict__ pooled) {
    int row = blockIdx.x;
    const float* vrow = var + (size_t)row * NPIX;
    const float* xrow = x + (size_t)row * NPIX;
    int tid = threadIdx.x;

    __shared__ unsigned hist[256];
    __shared__ unsigned s_prefix, s_remaining;
    __shared__ unsigned eq_idx[256];
    __shared__ unsigned eq_cnt;

    unsigned prefix = 0;
    unsigned remaining = TOPK;
    for (int pass = 0; pass < 4; ++pass) {
        int shift = 24 - 8 * pass;
        hist[tid] = 0;
        __syncthreads();
        for (int i = tid; i < NPIX; i += 256) {
            unsigned m = monot(vrow[i]);
            bool ok = (pass == 0) || ((m >> (shift + 8)) == prefix);
            if (ok) atomicAdd(&hist[(m >> shift) & 255u], 1u);
        }
        __syncthreads();
        if (tid == 0) {
            unsigned cum = 0; int bs = 255;
            for (; bs >= 0; --bs) {
                if (cum + hist[bs] >= remaining) break;
                cum += hist[bs];
            }
            s_prefix = (prefix << 8) | (unsigned)bs;
            s_remaining = remaining - cum;
        }
        __syncthreads();
        prefix = s_prefix;
        remaining = s_remaining;
        __syncthreads();
    }
    unsigned thr = prefix;
    unsigned need_eq = remaining;

    if (tid == 0) eq_cnt = 0;
    __syncthreads();
    for (int i = tid; i < NPIX; i += 256) {
        if (monot(vrow[i]) == thr) {
            unsigned pos = atomicAdd(&eq_cnt, 1u);
            if (pos < 256) eq_idx[pos] = (unsigned)i;
        }
    }
    __syncthreads();
    int ecnt = (int)min(eq_cnt, 256u);
    if (tid == 0) {
        for (int a = 1; a < ecnt; ++a) {
            unsigned key = eq_idx[a]; int q = a - 1;
            while (q >= 0 && eq_idx[q] > key) { eq_idx[q + 1] = eq_idx[q]; --q; }
            eq_idx[q + 1] = key;
        }
    }
    __syncthreads();

    int wy = tid >> 4, wx = tid & 15;
    float s = 0.f;
    for (int dy = 0; dy < WSZ; ++dy) {
        int y = wy * WSZ + dy;
        for (int dx = 0; dx < WSZ; ++dx) {
            int xg = wx * WSZ + dx;
            int i = y * IW + xg;
            unsigned m = monot(vrow[i]);
            float mult;
            if (m > thr) mult = 1.0f;
            else if (m < thr) mult = 0.6f;
            else {
                unsigned rank = 0;
                for (int e = 0; e < ecnt; ++e) if (eq_idx[e] < (unsigned)i) ++rank;
                mult = (rank < need_eq) ? 1.0f : 0.6f;
            }
            s += xrow[i] * mult;
        }
    }
    s *= (1.0f / 64.0f);
    float pv = s > 0.f ? s : 0.01f * s;
    pooled[(size_t)row * NWIN + tid] = pv;
}

// ---------------------------------------------------------------------------
// K2: per (b, window): dots with bias_w/scale_w -> sb[p][win] = {sx,sy,bx/16,by/16}
// ---------------------------------------------------------------------------
__global__ __launch_bounds__(64) void k2_sb(const float* __restrict__ pooled,
                                            const float* __restrict__ bias_w,
                                            const float* __restrict__ bias_b,
                                            const float* __restrict__ scale_w,
                                            const float* __restrict__ scale_b,
                                            float* __restrict__ sb) {
    int blk = blockIdx.x;
    int b = blk / NWIN, w = blk % NWIN;
    int tid = threadIdx.x;
    __shared__ float pcol[CCH];
    __shared__ float res[24];
    for (int c = tid; c < CCH; c += 64) pcol[c] = pooled[(size_t)(b * CCH + c) * NWIN + w];
    __syncthreads();
    if (tid < 24) {
        bool isScale = tid >= 12;
        int o = isScale ? tid - 12 : tid;
        const float* Wt = isScale ? scale_w : bias_w;
        float acc = 0.f;
        for (int c = 0; c < CCH; ++c) acc += Wt[o * CCH + c] * pcol[c];
        acc += (isScale ? scale_b[o] : bias_b[o]);
        if (!isScale) acc *= (1.0f / 16.0f);
        res[tid] = acc;
    }
    __syncthreads();
    if (tid < NH) {
        int p = b * NH + tid;
        float4 v;
        v.x = res[12 + 2 * tid];
        v.y = res[12 + 2 * tid + 1];
        v.z = res[2 * tid];
        v.w = res[2 * tid + 1];
        ((float4*)sb)[(size_t)p * NWIN + w] = v;
    }
}

// ---------------------------------------------------------------------------
// K3: qkv 1x1 conv via bf16 MFMA. Per block: 192 out-ch (one of q/k/v) x 128 px.
// ---------------------------------------------------------------------------
__global__ __launch_bounds__(256) void k3_mfma(const float* __restrict__ x,
                                               const float* __restrict__ qkv_w,
                                               const float* __restrict__ qkv_b,
                                               unsigned short* __restrict__ qb,
                                               unsigned short* __restrict__ kb,
                                               unsigned short* __restrict__ vb) {
    constexpr int BN = 128, KC = 64, KCP = 72;
    __shared__ unsigned short Ws[CCH][KCP];   // [o][k], k-contiguous
    __shared__ unsigned short Xt[BN][KCP];    // [px][k], k-contiguous
    int px0 = blockIdx.x * BN;
    int t = blockIdx.y, b = blockIdx.z;
    int o0 = t * CCH;
    int tid = threadIdx.x;
    int wv = tid >> 6, lane = tid & 63, lr = lane & 15, lg = lane >> 4;

    f32x4 acc[3][8];
#pragma unroll
    for (int i = 0; i < 3; ++i)
#pragma unroll
        for (int j = 0; j < 8; ++j) acc[i][j] = (f32x4){0.f, 0.f, 0.f, 0.f};

    int spx = tid & 127, skg = tid >> 7;   // staging: px, k-half

    for (int k0 = 0; k0 < CCH; k0 += KC) {
        // W stage: 192x64 via float4
        for (int idx4 = tid; idx4 < CCH * KC / 4; idx4 += 256) {
            int o = idx4 >> 4, k4 = (idx4 & 15) * 4;
            float4 w4 = *(const float4*)&qkv_w[(size_t)(o0 + o) * CCH + k0 + k4];
            u16x4 pk = { f2bf(w4.x), f2bf(w4.y), f2bf(w4.z), f2bf(w4.w) };
            *(u16x4*)&Ws[o][k4] = pk;
        }
        // X stage (transpose): thread owns px=spx, loads 32 k-rows, packs b128 writes
        {
            const float* xcol = &x[(size_t)(b * CCH + k0 + skg * 32) * NPIX + px0 + spx];
#pragma unroll
            for (int j8 = 0; j8 < 4; ++j8) {
                u16x8 pk;
#pragma unroll
                for (int j = 0; j < 8; ++j) pk[j] = f2bf(xcol[(size_t)(j8 * 8 + j) * NPIX]);
                *(u16x8*)&Xt[spx][skg * 32 + j8 * 8] = pk;
            }
        }
        __syncthreads();
#pragma unroll
        for (int kk = 0; kk < KC; kk += 32) {
            bf16x8 af[3], bfr[8];
#pragma unroll
            for (int i = 0; i < 3; ++i)
                af[i] = *(const bf16x8*)&Ws[wv * 48 + i * 16 + lr][kk + lg * 8];
#pragma unroll
            for (int j = 0; j < 8; ++j)
                bfr[j] = *(const bf16x8*)&Xt[j * 16 + lr][kk + lg * 8];
#pragma unroll
            for (int i = 0; i < 3; ++i)
#pragma unroll
                for (int j = 0; j < 8; ++j)
                    acc[i][j] = __builtin_amdgcn_mfma_f32_16x16x32_bf16(af[i], bfr[j], acc[i][j], 0, 0, 0);
        }
        __syncthreads();
    }

    unsigned short* dst = (t == 0) ? qb : (t == 1) ? kb : vb;
#pragma unroll
    for (int i = 0; i < 3; ++i) {
        int och = wv * 48 + i * 16 + lg * 4;
#pragma unroll
        for (int r = 0; r < 4; ++r) {
            float bias = qkv_b[o0 + och + r];
            size_t base = (size_t)(b * CCH + och + r) * NPIX + px0 + lr;
#pragma unroll
            for (int j = 0; j < 8; ++j)
                dst[base + j * 16] = f2bf(acc[i][j][r] + bias);
        }
    }
}

// ---------------------------------------------------------------------------
// K4: per (b, head, window): bilinear-sample k,v, windowed attention with
//     relative bias; writes att (bf16) back into the q buffer (same layout).
// ---------------------------------------------------------------------------
__global__ __launch_bounds__(256) void k4_attn(unsigned short* __restrict__ qatt,
                                               const unsigned short* __restrict__ kb,
                                               const unsigned short* __restrict__ vb,
                                               const float* __restrict__ sb,
                                               const float* __restrict__ rel_table) {
    int win = blockIdx.x, head = blockIdx.y, b = blockIdx.z;
    int wy = win >> 4, wx = win & 15;
    int p = b * NH + head;
    int tid = threadIdx.x;

    __shared__ float qw[64][33];
    __shared__ float kw[64][33];
    __shared__ float vw[64][33];
    __shared__ float S[64][65];

    // q tile load (vectorized 16B)
    {
        int d = tid >> 3, dy = tid & 7;
        const unsigned short* qrow = qatt + ((size_t)(p * HDIM + d) * IH + wy * WSZ + dy) * IW + wx * WSZ;
        u16x8 qv = *(const u16x8*)qrow;
#pragma unroll
        for (int dx = 0; dx < 8; ++dx) qw[dy * 8 + dx][d] = bf2f(qv[dx]);
    }

    // bilinear sampling of k,v
    {
        float4 sbv = ((const float4*)sb)[(size_t)p * NWIN + win];
        int j = tid >> 2, qq = tid & 3;
        int dy = j >> 3, dx = j & 7;
        int yg = wy * WSZ + dy, xg = wx * WSZ + dx;
        float gx = -1.0f + xg * (2.0f / 127.0f) + ((float)dx - 3.5f) * (2.0f / 127.0f) * sbv.x + sbv.z;
        float gy = -1.0f + yg * (2.0f / 127.0f) + ((float)dy - 3.5f) * (2.0f / 127.0f) * sbv.y + sbv.w;
        float fx = (gx + 1.0f) * 0.5f * 127.0f;
        float fy = (gy + 1.0f) * 0.5f * 127.0f;
        float x0f = floorf(fx), y0f = floorf(fy);
        float wx1 = fx - x0f, wy1 = fy - y0f;
        int ix0 = (int)x0f, iy0 = (int)y0f;
        int ix1 = ix0 + 1, iy1 = iy0 + 1;
        float w00 = (1.0f - wx1) * (1.0f - wy1);
        float w10 = wx1 * (1.0f - wy1);
        float w01 = (1.0f - wx1) * wy1;
        float w11 = wx1 * wy1;
        bool vX0 = (ix0 >= 0) && (ix0 < IW), vX1 = (ix1 >= 0) && (ix1 < IW);
        bool vY0 = (iy0 >= 0) && (iy0 < IH), vY1 = (iy1 >= 0) && (iy1 < IH);
        if (!(vX0 && vY0)) w00 = 0.f;
        if (!(vX1 && vY0)) w10 = 0.f;
        if (!(vX0 && vY1)) w01 = 0.f;
        if (!(vX1 && vY1)) w11 = 0.f;
        int cx0 = min(max(ix0, 0), IW - 1), cx1 = min(max(ix1, 0), IW - 1);
        int cy0 = min(max(iy0, 0), IH - 1), cy1 = min(max(iy1, 0), IH - 1);
        size_t o00 = (size_t)cy0 * IW + cx0, o10 = (size_t)cy0 * IW + cx1;
        size_t o01 = (size_t)cy1 * IW + cx0, o11 = (size_t)cy1 * IW + cx1;
        const unsigned short* kbase = kb + (size_t)(p * HDIM) * NPIX;
        const unsigned short* vbase = vb + (size_t)(p * HDIM) * NPIX;
        for (int c = qq * 8; c < qq * 8 + 8; ++c) {
            size_t coff = (size_t)c * NPIX;
            float kval = w00 * bf2f(kbase[coff + o00]) + w10 * bf2f(kbase[coff + o10]) +
                         w01 * bf2f(kbase[coff + o01]) + w11 * bf2f(kbase[coff + o11]);
            float vval = w00 * bf2f(vbase[coff + o00]) + w10 * bf2f(vbase[coff + o10]) +
                         w01 * bf2f(vbase[coff + o01]) + w11 * bf2f(vbase[coff + o11]);
            kw[j][c] = kval;
            vw[j][c] = vval;
        }
    }
    __syncthreads();

    // scores
    {
        int i = tid & 63;
        int jb0 = (tid >> 6) * 16;
        float qreg[32];
#pragma unroll
        for (int d = 0; d < 32; ++d) qreg[d] = qw[i][d];
        int cih = i >> 3, ciw = i & 7;
        for (int jj = 0; jj < 16; ++jj) {
            int j = jb0 + jj;
            float a = 0.f;
#pragma unroll
            for (int d = 0; d < 32; ++d) a += qreg[d] * kw[j][d];
            int cjh = j >> 3, cjw = j & 7;
            int ridx = (cih - cjh + 7) * 15 + (ciw - cjw + 7);
            S[i][j] = a * 0.17677669529663688f + rel_table[ridx * NH + head];
        }
    }
    __syncthreads();

    // softmax (4 lanes per row)
    {
        int row = tid >> 2, qq = tid & 3;
        float mx = -1e30f;
#pragma unroll
        for (int j = qq * 16; j < qq * 16 + 16; ++j) mx = fmaxf(mx, S[row][j]);
        mx = fmaxf(mx, __shfl_xor(mx, 1));
        mx = fmaxf(mx, __shfl_xor(mx, 2));
        float sum = 0.f;
#pragma unroll
        for (int j = qq * 16; j < qq * 16 + 16; ++j) { float e = __expf(S[row][j] - mx); S[row][j] = e; sum += e; }
        sum += __shfl_xor(sum, 1);
        sum += __shfl_xor(sum, 2);
        float inv = 1.0f / sum;
#pragma unroll
        for (int j = qq * 16; j < qq * 16 + 16; ++j) S[row][j] *= inv;
    }
    __syncthreads();

    // PV + write att (bf16) into q buffer at this window's pixels
    {
        int i = tid >> 2;
        int d0 = (tid & 3) * 8;
        float acc[8] = {};
        for (int j = 0; j < 64; ++j) {
            float a = S[i][j];
#pragma unroll
            for (int dd = 0; dd < 8; ++dd) acc[dd] += a * vw[j][d0 + dd];
        }
        int dy = i >> 3, dx = i & 7;
        int yg = wy * WSZ + dy, xg = wx * WSZ + dx;
#pragma unroll
        for (int dd = 0; dd < 8; ++dd)
            qatt[((size_t)(p * HDIM + d0 + dd) * IH + yg) * IW + xg] = f2bf(acc[dd]);
    }
}

// ---------------------------------------------------------------------------
// K5: projection via bf16 MFMA: out = proj_w @ att + proj_b. att read as bf16
//     from the q buffer; f32 output to d_out (no in-place hazard).
// ---------------------------------------------------------------------------
__global__ __launch_bounds__(256) void k5_mfma(const unsigned short* __restrict__ att,
                                               const float* __restrict__ proj_w,
                                               const float* __restrict__ proj_b,
                                               float* __restrict__ out) {
    constexpr int BN = 128, KC = 64, KCP = 72;
    __shared__ unsigned short Ws[CCH][KCP];
    __shared__ unsigned short Xt[BN][KCP];
    int px0 = blockIdx.x * BN;
    int b = blockIdx.y;
    int tid = threadIdx.x;
    int wv = tid >> 6, lane = tid & 63, lr = lane & 15, lg = lane >> 4;

    f32x4 acc[3][8];
#pragma unroll
    for (int i = 0; i < 3; ++i)
#pragma unroll
        for (int j = 0; j < 8; ++j) acc[i][j] = (f32x4){0.f, 0.f, 0.f, 0.f};

    int spx = tid & 127, skg = tid >> 7;

    for (int k0 = 0; k0 < CCH; k0 += KC) {
        for (int idx4 = tid; idx4 < CCH * KC / 4; idx4 += 256) {
            int o = idx4 >> 4, k4 = (idx4 & 15) * 4;
            float4 w4 = *(const float4*)&proj_w[(size_t)o * CCH + k0 + k4];
            u16x4 pk = { f2bf(w4.x), f2bf(w4.y), f2bf(w4.z), f2bf(w4.w) };
            *(u16x4*)&Ws[o][k4] = pk;
        }
        {
            const unsigned short* acol = att + (size_t)(b * CCH + k0 + skg * 32) * NPIX + px0 + spx;
#pragma unroll
            for (int j8 = 0; j8 < 4; ++j8) {
                u16x8 pk;
#pragma unroll
                for (int j = 0; j < 8; ++j) pk[j] = acol[(size_t)(j8 * 8 + j) * NPIX];
                *(u16x8*)&Xt[spx][skg * 32 + j8 * 8] = pk;
            }
        }
        __syncthreads();
#pragma unroll
        for (int kk = 0; kk < KC; kk += 32) {
            bf16x8 af[3], bfr[8];
#pragma unroll
            for (int i = 0; i < 3; ++i)
                af[i] = *(const bf16x8*)&Ws[wv * 48 + i * 16 + lr][kk + lg * 8];
#pragma unroll
            for (int j = 0; j < 8; ++j)
                bfr[j] = *(const bf16x8*)&Xt[j * 16 + lr][kk + lg * 8];
#pragma unroll
            for (int i = 0; i < 3; ++i)
#pragma unroll
                for (int j = 0; j < 8; ++j)
                    acc[i][j] = __builtin_amdgcn_mfma_f32_16x16x32_bf16(af[i], bfr[j], acc[i][j], 0, 0, 0);
        }
        __syncthreads();
    }

#pragma unroll
    for (int i = 0; i < 3; ++i) {
        int och = wv * 48 + i * 16 + lg * 4;
#pragma unroll
        for (int r = 0; r < 4; ++r) {
            float bias = proj_b[och + r];
            size_t base = (size_t)(b * CCH + och + r) * NPIX + px0 + lr;
#pragma unroll
            for (int j = 0; j < 8; ++j)
                out[base + j * 16] = acc[i][j][r] + bias;
        }
    }
}

// ---------------------------------------------------------------------------
extern "C" void kernel_launch(void* const* d_in, const int* in_sizes, int n_in,
                              void* d_out, int out_size, void* d_ws, size_t ws_size,
                              hipStream_t stream) {
    const float* x = (const float*)d_in[0];
    const float* var = (const float*)d_in[1];
    const float* qkv_w = (const float*)d_in[2];
    const float* qkv_b = (const float*)d_in[3];
    const float* bias_w = (const float*)d_in[4];
    const float* bias_b = (const float*)d_in[5];
    const float* scale_w = (const float*)d_in[6];
    const float* scale_b = (const float*)d_in[7];
    const float* proj_w = (const float*)d_in[8];
    const float* proj_b = (const float*)d_in[9];
    const float* rel_table = (const float*)d_in[10];
    float* out = (float*)d_out;

    char* ws = (char*)d_ws;
    float* pooled = (float*)ws;                           // 393216 f32
    float* sb = (float*)(ws + 393216ull * 4);             // 49152 f32
    const size_t elemQ = (size_t)BB * CCH * NPIX;         // 25165824
    unsigned short* q = (unsigned short*)(ws + 1769472ull);
    unsigned short* k = q + elemQ;
    unsigned short* v = k + elemQ;

    size_t need = 1769472ull + 3ull * elemQ * 2;
    if (ws_size < need) return;

    k1_pool<<<dim3(BB * CCH), dim3(256), 0, stream>>>(x, var, pooled);
    k2_sb<<<dim3(BB * NWIN), dim3(64), 0, stream>>>(pooled, bias_w, bias_b, scale_w, scale_b, sb);
    k3_mfma<<<dim3(NPIX / 128, 3, BB), dim3(256), 0, stream>>>(x, qkv_w, qkv_b, q, k, v);
    k4_attn<<<dim3(NWIN, NH, BB), dim3(256), 0, stream>>>(q, k, v, sb, rel_table);
    k5_mfma<<<dim3(NPIX / 128, BB), dim3(256), 0, stream>>>(q, proj_w, proj_b, out);
}

// Round 3
// 735.766 us; speedup vs baseline: 1.7809x; 1.0350x over previous
//
#include <hip/hip_runtime.h>
#include <hip/hip_bf16.h>
#include <math.h>

constexpr int BB = 8, CCH = 192, IH = 128, IW = 128;
constexpr int WSZ = 8;
constexpr int NWIN = 256;
constexpr int NH = 6, HDIM = 32;
constexpr int NPIX = IH * IW;
constexpr int TOPK = 13107;

typedef __attribute__((ext_vector_type(8))) short bf16x8;
typedef __attribute__((ext_vector_type(4))) float f32x4;
typedef __attribute__((ext_vector_type(4))) unsigned short u16x4;
typedef __attribute__((ext_vector_type(8))) unsigned short u16x8;

__device__ __forceinline__ unsigned short f2bf(float f) {
    __hip_bfloat16 h = __float2bfloat16(f);
    return __builtin_bit_cast(unsigned short, h);
}
__device__ __forceinline__ float bf2f(unsigned short u) {
    return __uint_as_float((unsigned)u << 16);
}
__device__ __forceinline__ unsigned monot(float f) {
    unsigned u = __float_as_uint(f);
    return (u & 0x80000000u) ? ~u : (u | 0x80000000u);
}

// ---------------------------------------------------------------------------
// K1: per (b,c) row: exact top-k threshold on var (stable ties like lax.top_k),
//     then masked 8x8 avg-pool + leaky_relu -> pooled (b, c, 16, 16)
// ---------------------------------------------------------------------------
__global__ __launch_bounds__(256) void k1_pool(const float* __restrict__ x,
                                               const float* __restrict__ var,
                                               float* __restrict__ pooled) {
    int row = blockIdx.x;
    const float* vrow = var + (size_t)row * NPIX;
    const float* xrow = x + (size_t)row * NPIX;
    int tid = threadIdx.x;

    __shared__ unsigned hist[256];
    __shared__ unsigned s_prefix, s_remaining;
    __shared__ unsigned eq_idx[256];
    __shared__ unsigned eq_cnt;

    unsigned prefix = 0;
    unsigned remaining = TOPK;
    for (int pass = 0; pass < 4; ++pass) {
        int shift = 24 - 8 * pass;
        hist[tid] = 0;
        __syncthreads();
        for (int i = tid; i < NPIX; i += 256) {
            unsigned m = monot(vrow[i]);
            bool ok = (pass == 0) || ((m >> (shift + 8)) == prefix);
            if (ok) atomicAdd(&hist[(m >> shift) & 255u], 1u);
        }
        __syncthreads();
        if (tid == 0) {
            unsigned cum = 0; int bs = 255;
            for (; bs >= 0; --bs) {
                if (cum + hist[bs] >= remaining) break;
                cum += hist[bs];
            }
            s_prefix = (prefix << 8) | (unsigned)bs;
            s_remaining = remaining - cum;
        }
        __syncthreads();
        prefix = s_prefix;
        remaining = s_remaining;
        __syncthreads();
    }
    unsigned thr = prefix;
    unsigned need_eq = remaining;

    if (tid == 0) eq_cnt = 0;
    __syncthreads();
    for (int i = tid; i < NPIX; i += 256) {
        if (monot(vrow[i]) == thr) {
            unsigned pos = atomicAdd(&eq_cnt, 1u);
            if (pos < 256) eq_idx[pos] = (unsigned)i;
        }
    }
    __syncthreads();
    int ecnt = (int)min(eq_cnt, 256u);
    if (tid == 0) {
        for (int a = 1; a < ecnt; ++a) {
            unsigned key = eq_idx[a]; int q = a - 1;
            while (q >= 0 && eq_idx[q] > key) { eq_idx[q + 1] = eq_idx[q]; --q; }
            eq_idx[q + 1] = key;
        }
    }
    __syncthreads();

    int wy = tid >> 4, wx = tid & 15;
    float s = 0.f;
    for (int dy = 0; dy < WSZ; ++dy) {
        int y = wy * WSZ + dy;
        for (int dx = 0; dx < WSZ; ++dx) {
            int xg = wx * WSZ + dx;
            int i = y * IW + xg;
            unsigned m = monot(vrow[i]);
            float mult;
            if (m > thr) mult = 1.0f;
            else if (m < thr) mult = 0.6f;
            else {
                unsigned rank = 0;
                for (int e = 0; e < ecnt; ++e) if (eq_idx[e] < (unsigned)i) ++rank;
                mult = (rank < need_eq) ? 1.0f : 0.6f;
            }
            s += xrow[i] * mult;
        }
    }
    s *= (1.0f / 64.0f);
    float pv = s > 0.f ? s : 0.01f * s;
    pooled[(size_t)row * NWIN + tid] = pv;
}

// ---------------------------------------------------------------------------
// K2: per (b, window): dots with bias_w/scale_w -> sb[p][win] = {sx,sy,bx/16,by/16}
// ---------------------------------------------------------------------------
__global__ __launch_bounds__(64) void k2_sb(const float* __restrict__ pooled,
                                            const float* __restrict__ bias_w,
                                            const float* __restrict__ bias_b,
                                            const float* __restrict__ scale_w,
                                            const float* __restrict__ scale_b,
                                            float* __restrict__ sb) {
    int blk = blockIdx.x;
    int b = blk / NWIN, w = blk % NWIN;
    int tid = threadIdx.x;
    __shared__ float pcol[CCH];
    __shared__ float res[24];
    for (int c = tid; c < CCH; c += 64) pcol[c] = pooled[(size_t)(b * CCH + c) * NWIN + w];
    __syncthreads();
    if (tid < 24) {
        bool isScale = tid >= 12;
        int o = isScale ? tid - 12 : tid;
        const float* Wt = isScale ? scale_w : bias_w;
        float acc = 0.f;
        for (int c = 0; c < CCH; ++c) acc += Wt[o * CCH + c] * pcol[c];
        acc += (isScale ? scale_b[o] : bias_b[o]);
        if (!isScale) acc *= (1.0f / 16.0f);
        res[tid] = acc;
    }
    __syncthreads();
    if (tid < NH) {
        int p = b * NH + tid;
        float4 v;
        v.x = res[12 + 2 * tid];
        v.y = res[12 + 2 * tid + 1];
        v.z = res[2 * tid];
        v.w = res[2 * tid + 1];
        ((float4*)sb)[(size_t)p * NWIN + w] = v;
    }
}

// ---------------------------------------------------------------------------
// K3: qkv 1x1 conv via bf16 MFMA, channel-last outputs:
//     q: (b, px, 192)   k/v: (b*NH+head, px, 32)
// ---------------------------------------------------------------------------
__global__ __launch_bounds__(256) void k3_mfma(const float* __restrict__ x,
                                               const float* __restrict__ qkv_w,
                                               const float* __restrict__ qkv_b,
                                               unsigned short* __restrict__ qb,
                                               unsigned short* __restrict__ kb,
                                               unsigned short* __restrict__ vb) {
    constexpr int BN = 128, KC = 64, KCP = 72;
    __shared__ unsigned short Ws[CCH][KCP];   // [o][k]
    __shared__ unsigned short Xt[BN][KCP];    // [px][k]
    int px0 = blockIdx.x * BN;
    int t = blockIdx.y, b = blockIdx.z;
    int o0 = t * CCH;
    int tid = threadIdx.x;
    int wv = tid >> 6, lane = tid & 63, lr = lane & 15, lg = lane >> 4;

    f32x4 acc[3][8];
#pragma unroll
    for (int i = 0; i < 3; ++i)
#pragma unroll
        for (int j = 0; j < 8; ++j) acc[i][j] = (f32x4){0.f, 0.f, 0.f, 0.f};

    int spx = tid & 127, skg = tid >> 7;

    for (int k0 = 0; k0 < CCH; k0 += KC) {
        for (int idx4 = tid; idx4 < CCH * KC / 4; idx4 += 256) {
            int o = idx4 >> 4, k4 = (idx4 & 15) * 4;
            float4 w4 = *(const float4*)&qkv_w[(size_t)(o0 + o) * CCH + k0 + k4];
            u16x4 pk = { f2bf(w4.x), f2bf(w4.y), f2bf(w4.z), f2bf(w4.w) };
            *(u16x4*)&Ws[o][k4] = pk;
        }
        {
            const float* xcol = &x[(size_t)(b * CCH + k0 + skg * 32) * NPIX + px0 + spx];
#pragma unroll
            for (int j8 = 0; j8 < 4; ++j8) {
                u16x8 pk;
#pragma unroll
                for (int j = 0; j < 8; ++j) pk[j] = f2bf(xcol[(size_t)(j8 * 8 + j) * NPIX]);
                *(u16x8*)&Xt[spx][skg * 32 + j8 * 8] = pk;
            }
        }
        __syncthreads();
#pragma unroll
        for (int kk = 0; kk < KC; kk += 32) {
            bf16x8 af[3], bfr[8];
#pragma unroll
            for (int i = 0; i < 3; ++i)
                af[i] = *(const bf16x8*)&Ws[wv * 48 + i * 16 + lr][kk + lg * 8];
#pragma unroll
            for (int j = 0; j < 8; ++j)
                bfr[j] = *(const bf16x8*)&Xt[j * 16 + lr][kk + lg * 8];
#pragma unroll
            for (int i = 0; i < 3; ++i)
#pragma unroll
                for (int j = 0; j < 8; ++j)
                    acc[i][j] = __builtin_amdgcn_mfma_f32_16x16x32_bf16(af[i], bfr[j], acc[i][j], 0, 0, 0);
        }
        __syncthreads();
    }

#pragma unroll
    for (int i = 0; i < 3; ++i) {
        int och = wv * 48 + i * 16 + lg * 4;   // 4 consecutive out channels
        float b0 = qkv_b[o0 + och], b1 = qkv_b[o0 + och + 1];
        float b2 = qkv_b[o0 + och + 2], b3 = qkv_b[o0 + och + 3];
#pragma unroll
        for (int j = 0; j < 8; ++j) {
            int px = px0 + lr + j * 16;
            u16x4 pk = { f2bf(acc[i][j][0] + b0), f2bf(acc[i][j][1] + b1),
                         f2bf(acc[i][j][2] + b2), f2bf(acc[i][j][3] + b3) };
            if (t == 0) {
                *(u16x4*)&qb[((size_t)b * NPIX + px) * CCH + och] = pk;
            } else {
                int head = och >> 5, d = och & 31;
                unsigned short* dst = (t == 1) ? kb : vb;
                *(u16x4*)&dst[(((size_t)(b * NH + head)) * NPIX + px) * HDIM + d] = pk;
            }
        }
    }
}

// ---------------------------------------------------------------------------
// K4: per (b, head, window): bilinear-sample k,v (channel-last), windowed
//     attention with relative bias; writes att (bf16, channel-last) into qb.
// ---------------------------------------------------------------------------
__global__ __launch_bounds__(256) void k4_attn(unsigned short* __restrict__ qatt,
                                               const unsigned short* __restrict__ kb,
                                               const unsigned short* __restrict__ vb,
                                               const float* __restrict__ sb,
                                               const float* __restrict__ rel_table) {
    int win = blockIdx.x, head = blockIdx.y, b = blockIdx.z;
    int wy = win >> 4, wx = win & 15;
    int p = b * NH + head;
    int tid = threadIdx.x;

    __shared__ float qw[64][33];
    __shared__ float kw[64][33];
    __shared__ float vw[64][33];
    __shared__ float S[64][65];

    int j = tid >> 2, qq = tid & 3;          // pixel-in-window, channel-quarter
    int dy = j >> 3, dx = j & 7;
    int yg = wy * WSZ + dy, xg = wx * WSZ + dx;
    int pixg = yg * IW + xg;

    // q tile load: 16B per thread
    {
        u16x8 qv = *(const u16x8*)&qatt[((size_t)b * NPIX + pixg) * CCH + head * HDIM + qq * 8];
#pragma unroll
        for (int c = 0; c < 8; ++c) qw[j][qq * 8 + c] = bf2f(qv[c]);
    }

    // bilinear sampling of k,v: 4 taps x 16B per tensor
    {
        float4 sbv = ((const float4*)sb)[(size_t)p * NWIN + win];
        float gx = -1.0f + xg * (2.0f / 127.0f) + ((float)dx - 3.5f) * (2.0f / 127.0f) * sbv.x + sbv.z;
        float gy = -1.0f + yg * (2.0f / 127.0f) + ((float)dy - 3.5f) * (2.0f / 127.0f) * sbv.y + sbv.w;
        float fx = (gx + 1.0f) * 0.5f * 127.0f;
        float fy = (gy + 1.0f) * 0.5f * 127.0f;
        float x0f = floorf(fx), y0f = floorf(fy);
        float wx1 = fx - x0f, wy1 = fy - y0f;
        int ix0 = (int)x0f, iy0 = (int)y0f;
        int ix1 = ix0 + 1, iy1 = iy0 + 1;
        float w00 = (1.0f - wx1) * (1.0f - wy1);
        float w10 = wx1 * (1.0f - wy1);
        float w01 = (1.0f - wx1) * wy1;
        float w11 = wx1 * wy1;
        bool vX0 = (ix0 >= 0) && (ix0 < IW), vX1 = (ix1 >= 0) && (ix1 < IW);
        bool vY0 = (iy0 >= 0) && (iy0 < IH), vY1 = (iy1 >= 0) && (iy1 < IH);
        if (!(vX0 && vY0)) w00 = 0.f;
        if (!(vX1 && vY0)) w10 = 0.f;
        if (!(vX0 && vY1)) w01 = 0.f;
        if (!(vX1 && vY1)) w11 = 0.f;
        int cx0 = min(max(ix0, 0), IW - 1), cx1 = min(max(ix1, 0), IW - 1);
        int cy0 = min(max(iy0, 0), IH - 1), cy1 = min(max(iy1, 0), IH - 1);
        size_t r00 = ((size_t)p * NPIX + cy0 * IW + cx0) * HDIM + qq * 8;
        size_t r10 = ((size_t)p * NPIX + cy0 * IW + cx1) * HDIM + qq * 8;
        size_t r01 = ((size_t)p * NPIX + cy1 * IW + cx0) * HDIM + qq * 8;
        size_t r11 = ((size_t)p * NPIX + cy1 * IW + cx1) * HDIM + qq * 8;
        u16x8 k00 = *(const u16x8*)&kb[r00], k10 = *(const u16x8*)&kb[r10];
        u16x8 k01 = *(const u16x8*)&kb[r01], k11 = *(const u16x8*)&kb[r11];
        u16x8 v00 = *(const u16x8*)&vb[r00], v10 = *(const u16x8*)&vb[r10];
        u16x8 v01 = *(const u16x8*)&vb[r01], v11 = *(const u16x8*)&vb[r11];
#pragma unroll
        for (int c = 0; c < 8; ++c) {
            kw[j][qq * 8 + c] = w00 * bf2f(k00[c]) + w10 * bf2f(k10[c]) +
                                w01 * bf2f(k01[c]) + w11 * bf2f(k11[c]);
            vw[j][qq * 8 + c] = w00 * bf2f(v00[c]) + w10 * bf2f(v10[c]) +
                                w01 * bf2f(v01[c]) + w11 * bf2f(v11[c]);
        }
    }
    __syncthreads();

    // scores
    {
        int i = tid & 63;
        int jb0 = (tid >> 6) * 16;
        float qreg[32];
#pragma unroll
        for (int d = 0; d < 32; ++d) qreg[d] = qw[i][d];
        int cih = i >> 3, ciw = i & 7;
        for (int jj = 0; jj < 16; ++jj) {
            int jn = jb0 + jj;
            float a = 0.f;
#pragma unroll
            for (int d = 0; d < 32; ++d) a += qreg[d] * kw[jn][d];
            int cjh = jn >> 3, cjw = jn & 7;
            int ridx = (cih - cjh + 7) * 15 + (ciw - cjw + 7);
            S[i][jn] = a * 0.17677669529663688f + rel_table[ridx * NH + head];
        }
    }
    __syncthreads();

    // softmax (4 lanes per row)
    {
        int row = tid >> 2;
        float mx = -1e30f;
#pragma unroll
        for (int jj = qq * 16; jj < qq * 16 + 16; ++jj) mx = fmaxf(mx, S[row][jj]);
        mx = fmaxf(mx, __shfl_xor(mx, 1));
        mx = fmaxf(mx, __shfl_xor(mx, 2));
        float sum = 0.f;
#pragma unroll
        for (int jj = qq * 16; jj < qq * 16 + 16; ++jj) { float e = __expf(S[row][jj] - mx); S[row][jj] = e; sum += e; }
        sum += __shfl_xor(sum, 1);
        sum += __shfl_xor(sum, 2);
        float inv = 1.0f / sum;
#pragma unroll
        for (int jj = qq * 16; jj < qq * 16 + 16; ++jj) S[row][jj] *= inv;
    }
    __syncthreads();

    // PV + att write (16B per thread), same addresses as this block's q tile
    {
        int i = tid >> 2;
        int d0 = (tid & 3) * 8;
        float acc[8] = {};
        for (int jn = 0; jn < 64; ++jn) {
            float a = S[i][jn];
#pragma unroll
            for (int dd = 0; dd < 8; ++dd) acc[dd] += a * vw[jn][d0 + dd];
        }
        int pdy = i >> 3, pdx = i & 7;
        int pix = (wy * WSZ + pdy) * IW + wx * WSZ + pdx;
        u16x8 pk;
#pragma unroll
        for (int dd = 0; dd < 8; ++dd) pk[dd] = f2bf(acc[dd]);
        *(u16x8*)&qatt[((size_t)b * NPIX + pix) * CCH + head * HDIM + d0] = pk;
    }
}

// ---------------------------------------------------------------------------
// K5: projection via bf16 MFMA: out = proj_w @ att + proj_b.
//     att channel-last (b, px, 192) -> direct u16x8 staging, f32 output.
// ---------------------------------------------------------------------------
__global__ __launch_bounds__(256) void k5_mfma(const unsigned short* __restrict__ att,
                                               const float* __restrict__ proj_w,
                                               const float* __restrict__ proj_b,
                                               float* __restrict__ out) {
    constexpr int BN = 128, KC = 64, KCP = 72;
    __shared__ unsigned short Ws[CCH][KCP];
    __shared__ unsigned short Xt[BN][KCP];
    int px0 = blockIdx.x * BN;
    int b = blockIdx.y;
    int tid = threadIdx.x;
    int wv = tid >> 6, lane = tid & 63, lr = lane & 15, lg = lane >> 4;

    f32x4 acc[3][8];
#pragma unroll
    for (int i = 0; i < 3; ++i)
#pragma unroll
        for (int j = 0; j < 8; ++j) acc[i][j] = (f32x4){0.f, 0.f, 0.f, 0.f};

    int spx = tid & 127, skg = tid >> 7;

    for (int k0 = 0; k0 < CCH; k0 += KC) {
        for (int idx4 = tid; idx4 < CCH * KC / 4; idx4 += 256) {
            int o = idx4 >> 4, k4 = (idx4 & 15) * 4;
            float4 w4 = *(const float4*)&proj_w[(size_t)o * CCH + k0 + k4];
            u16x4 pk = { f2bf(w4.x), f2bf(w4.y), f2bf(w4.z), f2bf(w4.w) };
            *(u16x4*)&Ws[o][k4] = pk;
        }
        {
            const unsigned short* arow = &att[((size_t)b * NPIX + px0 + spx) * CCH + k0 + skg * 32];
#pragma unroll
            for (int j8 = 0; j8 < 4; ++j8)
                *(u16x8*)&Xt[spx][skg * 32 + j8 * 8] = *(const u16x8*)&arow[j8 * 8];
        }
        __syncthreads();
#pragma unroll
        for (int kk = 0; kk < KC; kk += 32) {
            bf16x8 af[3], bfr[8];
#pragma unroll
            for (int i = 0; i < 3; ++i)
                af[i] = *(const bf16x8*)&Ws[wv * 48 + i * 16 + lr][kk + lg * 8];
#pragma unroll
            for (int j = 0; j < 8; ++j)
                bfr[j] = *(const bf16x8*)&Xt[j * 16 + lr][kk + lg * 8];
#pragma unroll
            for (int i = 0; i < 3; ++i)
#pragma unroll
                for (int j = 0; j < 8; ++j)
                    acc[i][j] = __builtin_amdgcn_mfma_f32_16x16x32_bf16(af[i], bfr[j], acc[i][j], 0, 0, 0);
        }
        __syncthreads();
    }

#pragma unroll
    for (int i = 0; i < 3; ++i) {
        int och = wv * 48 + i * 16 + lg * 4;
#pragma unroll
        for (int r = 0; r < 4; ++r) {
            float bias = proj_b[och + r];
            size_t base = (size_t)(b * CCH + och + r) * NPIX + px0 + lr;
#pragma unroll
            for (int j = 0; j < 8; ++j)
                out[base + j * 16] = acc[i][j][r] + bias;
        }
    }
}

// ---------------------------------------------------------------------------
extern "C" void kernel_launch(void* const* d_in, const int* in_sizes, int n_in,
                              void* d_out, int out_size, void* d_ws, size_t ws_size,
                              hipStream_t stream) {
    const float* x = (const float*)d_in[0];
    const float* var = (const float*)d_in[1];
    const float* qkv_w = (const float*)d_in[2];
    const float* qkv_b = (const float*)d_in[3];
    const float* bias_w = (const float*)d_in[4];
    const float* bias_b = (const float*)d_in[5];
    const float* scale_w = (const float*)d_in[6];
    const float* scale_b = (const float*)d_in[7];
    const float* proj_w = (const float*)d_in[8];
    const float* proj_b = (const float*)d_in[9];
    const float* rel_table = (const float*)d_in[10];
    float* out = (float*)d_out;

    char* ws = (char*)d_ws;
    float* pooled = (float*)ws;                           // 393216 f32
    float* sb = (float*)(ws + 393216ull * 4);             // 49152 f32
    const size_t elemQ = (size_t)BB * CCH * NPIX;         // 25165824
    unsigned short* q = (unsigned short*)(ws + 1769472ull);
    unsigned short* k = q + elemQ;
    unsigned short* v = k + elemQ;

    size_t need = 1769472ull + 3ull * elemQ * 2;
    if (ws_size < need) return;

    k1_pool<<<dim3(BB * CCH), dim3(256), 0, stream>>>(x, var, pooled);
    k2_sb<<<dim3(BB * NWIN), dim3(64), 0, stream>>>(pooled, bias_w, bias_b, scale_w, scale_b, sb);
    k3_mfma<<<dim3(NPIX / 128, 3, BB), dim3(256), 0, stream>>>(x, qkv_w, qkv_b, q, k, v);
    k4_attn<<<dim3(NWIN, NH, BB), dim3(256), 0, stream>>>(q, k, v, sb, rel_table);
    k5_mfma<<<dim3(NPIX / 128, BB), dim3(256), 0, stream>>>(q, proj_w, proj_b, out);
}

// Round 4
// 468.779 us; speedup vs baseline: 2.7951x; 1.5695x over previous
//
#include <hip/hip_runtime.h>
#include <hip/hip_bf16.h>
#include <math.h>

constexpr int BB = 8, CCH = 192, IH = 128, IW = 128;
constexpr int WSZ = 8;
constexpr int NWIN = 256;
constexpr int NH = 6, HDIM = 32;
constexpr int NPIX = IH * IW;
constexpr int TOPK = 13107;

typedef __attribute__((ext_vector_type(8))) short bf16x8;
typedef __attribute__((ext_vector_type(4))) float f32x4;
typedef __attribute__((ext_vector_type(4))) unsigned short u16x4;
typedef __attribute__((ext_vector_type(8))) unsigned short u16x8;

__device__ __forceinline__ unsigned short f2bf(float f) {
    __hip_bfloat16 h = __float2bfloat16(f);
    return __builtin_bit_cast(unsigned short, h);
}
__device__ __forceinline__ float bf2f(unsigned short u) {
    return __uint_as_float((unsigned)u << 16);
}
__device__ __forceinline__ unsigned monot(float f) {
    unsigned u = __float_as_uint(f);
    return (u & 0x80000000u) ? ~u : (u | 0x80000000u);
}

// ---------------------------------------------------------------------------
// K1: per (b,c) row: exact top-k threshold on var (register-resident keys),
//     then masked 8x8 avg-pool + leaky_relu -> pooled (b, c, 16, 16)
// ---------------------------------------------------------------------------
__global__ __launch_bounds__(256) void k1_pool(const float* __restrict__ x,
                                               const float* __restrict__ var,
                                               float* __restrict__ pooled) {
    int row = blockIdx.x;
    const float* vrow = var + (size_t)row * NPIX;
    const float* xrow = x + (size_t)row * NPIX;
    int tid = threadIdx.x;

    __shared__ unsigned hist[256];
    __shared__ unsigned s_prefix, s_remaining;
    __shared__ unsigned eq_idx[256];
    __shared__ unsigned eq_cnt;
    __shared__ float pooled_s[256];

    unsigned m[64];
#pragma unroll
    for (int j = 0; j < 64; ++j) m[j] = monot(vrow[tid + 256 * j]);

    unsigned prefix = 0, remaining = TOPK;
    for (int pass = 0; pass < 4; ++pass) {
        int shift = 24 - 8 * pass;
        hist[tid] = 0;
        __syncthreads();
#pragma unroll
        for (int j = 0; j < 64; ++j) {
            bool ok = (pass == 0) || ((m[j] >> (shift + 8)) == prefix);
            if (ok) atomicAdd(&hist[(m[j] >> shift) & 255u], 1u);
        }
        __syncthreads();
        if (tid == 0) {
            unsigned cum = 0; int bs = 255;
            for (; bs >= 0; --bs) {
                if (cum + hist[bs] >= remaining) break;
                cum += hist[bs];
            }
            s_prefix = (prefix << 8) | (unsigned)bs;
            s_remaining = remaining - cum;
        }
        __syncthreads();
        prefix = s_prefix;
        remaining = s_remaining;
        __syncthreads();
    }
    unsigned thr = prefix;
    unsigned need_eq = remaining;

    if (tid == 0) eq_cnt = 0;
    __syncthreads();
#pragma unroll
    for (int j = 0; j < 64; ++j) {
        if (m[j] == thr) {
            unsigned pos = atomicAdd(&eq_cnt, 1u);
            if (pos < 256) eq_idx[pos] = (unsigned)(tid + 256 * j);
        }
    }
    __syncthreads();
    int ecnt = (int)min(eq_cnt, 256u);
    if (tid == 0) {
        for (int a = 1; a < ecnt; ++a) {
            unsigned key = eq_idx[a]; int q = a - 1;
            while (q >= 0 && eq_idx[q] > key) { eq_idx[q + 1] = eq_idx[q]; --q; }
            eq_idx[q + 1] = key;
        }
    }
    pooled_s[tid] = 0.f;
    __syncthreads();

    int wxs = (tid & 127) >> 3;
#pragma unroll
    for (int g = 0; g < 16; ++g) {          // wy = g (derivation: y=(tid>>7)+2j, wy=j>>2)
        float s = 0.f;
#pragma unroll
        for (int jj = 0; jj < 4; ++jj) {
            int j = g * 4 + jj;
            int i = tid + 256 * j;
            unsigned mm = m[j];
            float mult;
            if (mm > thr) mult = 1.0f;
            else if (mm < thr) mult = 0.6f;
            else {
                unsigned rank = 0;
                for (int e = 0; e < ecnt; ++e) if (eq_idx[e] < (unsigned)i) ++rank;
                mult = (rank < need_eq) ? 1.0f : 0.6f;
            }
            s += xrow[i] * mult;
        }
        atomicAdd(&pooled_s[g * 16 + wxs], s);
    }
    __syncthreads();
    float pv = pooled_s[tid] * (1.0f / 64.0f);
    pv = pv > 0.f ? pv : 0.01f * pv;
    pooled[(size_t)row * NWIN + tid] = pv;
}

// ---------------------------------------------------------------------------
// K2: per (b, window): dots with bias_w/scale_w -> sb[p][win] = {sx,sy,bx/16,by/16}
// ---------------------------------------------------------------------------
__global__ __launch_bounds__(64) void k2_sb(const float* __restrict__ pooled,
                                            const float* __restrict__ bias_w,
                                            const float* __restrict__ bias_b,
                                            const float* __restrict__ scale_w,
                                            const float* __restrict__ scale_b,
                                            float* __restrict__ sb) {
    int blk = blockIdx.x;
    int b = blk / NWIN, w = blk % NWIN;
    int tid = threadIdx.x;
    __shared__ float pcol[CCH];
    __shared__ float res[24];
    for (int c = tid; c < CCH; c += 64) pcol[c] = pooled[(size_t)(b * CCH + c) * NWIN + w];
    __syncthreads();
    if (tid < 24) {
        bool isScale = tid >= 12;
        int o = isScale ? tid - 12 : tid;
        const float* Wt = isScale ? scale_w : bias_w;
        float acc = 0.f;
        for (int c = 0; c < CCH; ++c) acc += Wt[o * CCH + c] * pcol[c];
        acc += (isScale ? scale_b[o] : bias_b[o]);
        if (!isScale) acc *= (1.0f / 16.0f);
        res[tid] = acc;
    }
    __syncthreads();
    if (tid < NH) {
        int p = b * NH + tid;
        float4 v;
        v.x = res[12 + 2 * tid];
        v.y = res[12 + 2 * tid + 1];
        v.z = res[2 * tid];
        v.w = res[2 * tid + 1];
        ((float4*)sb)[(size_t)p * NWIN + w] = v;
    }
}

// ---------------------------------------------------------------------------
// K3: qkv 1x1 conv via bf16 MFMA, channel-last outputs:
//     q: (b, px, 192)   k/v: (b*NH+head, px, 32)
// ---------------------------------------------------------------------------
__global__ __launch_bounds__(256) void k3_mfma(const float* __restrict__ x,
                                               const float* __restrict__ qkv_w,
                                               const float* __restrict__ qkv_b,
                                               unsigned short* __restrict__ qb,
                                               unsigned short* __restrict__ kb,
                                               unsigned short* __restrict__ vb) {
    constexpr int BN = 128, KC = 64, KCP = 72;
    __shared__ unsigned short Ws[CCH][KCP];   // [o][k]
    __shared__ unsigned short Xt[BN][KCP];    // [px][k]
    int px0 = blockIdx.x * BN;
    int t = blockIdx.y, b = blockIdx.z;
    int o0 = t * CCH;
    int tid = threadIdx.x;
    int wv = tid >> 6, lane = tid & 63, lr = lane & 15, lg = lane >> 4;

    f32x4 acc[3][8];
#pragma unroll
    for (int i = 0; i < 3; ++i)
#pragma unroll
        for (int j = 0; j < 8; ++j) acc[i][j] = (f32x4){0.f, 0.f, 0.f, 0.f};

    int spx = tid & 127, skg = tid >> 7;

    for (int k0 = 0; k0 < CCH; k0 += KC) {
        for (int idx4 = tid; idx4 < CCH * KC / 4; idx4 += 256) {
            int o = idx4 >> 4, k4 = (idx4 & 15) * 4;
            float4 w4 = *(const float4*)&qkv_w[(size_t)(o0 + o) * CCH + k0 + k4];
            u16x4 pk = { f2bf(w4.x), f2bf(w4.y), f2bf(w4.z), f2bf(w4.w) };
            *(u16x4*)&Ws[o][k4] = pk;
        }
        {
            const float* xcol = &x[(size_t)(b * CCH + k0 + skg * 32) * NPIX + px0 + spx];
#pragma unroll
            for (int j8 = 0; j8 < 4; ++j8) {
                u16x8 pk;
#pragma unroll
                for (int j = 0; j < 8; ++j) pk[j] = f2bf(xcol[(size_t)(j8 * 8 + j) * NPIX]);
                *(u16x8*)&Xt[spx][skg * 32 + j8 * 8] = pk;
            }
        }
        __syncthreads();
#pragma unroll
        for (int kk = 0; kk < KC; kk += 32) {
            bf16x8 af[3], bfr[8];
#pragma unroll
            for (int i = 0; i < 3; ++i)
                af[i] = *(const bf16x8*)&Ws[wv * 48 + i * 16 + lr][kk + lg * 8];
#pragma unroll
            for (int j = 0; j < 8; ++j)
                bfr[j] = *(const bf16x8*)&Xt[j * 16 + lr][kk + lg * 8];
#pragma unroll
            for (int i = 0; i < 3; ++i)
#pragma unroll
                for (int j = 0; j < 8; ++j)
                    acc[i][j] = __builtin_amdgcn_mfma_f32_16x16x32_bf16(af[i], bfr[j], acc[i][j], 0, 0, 0);
        }
        __syncthreads();
    }

#pragma unroll
    for (int i = 0; i < 3; ++i) {
        int och = wv * 48 + i * 16 + lg * 4;
        float b0 = qkv_b[o0 + och], b1 = qkv_b[o0 + och + 1];
        float b2 = qkv_b[o0 + och + 2], b3 = qkv_b[o0 + och + 3];
#pragma unroll
        for (int j = 0; j < 8; ++j) {
            int px = px0 + lr + j * 16;
            u16x4 pk = { f2bf(acc[i][j][0] + b0), f2bf(acc[i][j][1] + b1),
                         f2bf(acc[i][j][2] + b2), f2bf(acc[i][j][3] + b3) };
            if (t == 0) {
                *(u16x4*)&qb[((size_t)b * NPIX + px) * CCH + och] = pk;
            } else {
                int head = och >> 5, d = och & 31;
                unsigned short* dst = (t == 1) ? kb : vb;
                *(u16x4*)&dst[(((size_t)(b * NH + head)) * NPIX + px) * HDIM + d] = pk;
            }
        }
    }
}

// ---------------------------------------------------------------------------
// K4: wave-per-window MFMA attention. S^T = K_samp . Q^T (keys lane-local-ish),
//     softmax via 16 in-reg + shfl_xor(16,32), PV via MFMA with P,V in LDS.
//     Writes att (bf16, channel-last) into qb.
// ---------------------------------------------------------------------------
__global__ __launch_bounds__(256) void k4_attn(unsigned short* __restrict__ qatt,
                                               const unsigned short* __restrict__ kb,
                                               const unsigned short* __restrict__ vb,
                                               const float* __restrict__ sb,
                                               const float* __restrict__ rel_table) {
    int tid = threadIdx.x;
    int wv = tid >> 6, lane = tid & 63, lr = lane & 15, lg = lane >> 4;
    int head = blockIdx.y, b = blockIdx.z;
    int win = blockIdx.x * 4 + wv;
    int wy = win >> 4, wx = win & 15;
    int p = b * NH + head;

    __shared__ float rel_s[225];
    __shared__ unsigned short Vl[4][64][33];   // [wave][key px][d]
    __shared__ unsigned short Pl[4][64][68];   // [wave][query][key]

    if (tid < 225) rel_s[tid] = rel_table[tid * NH + head];

    // Q fragments (B-operand: B[k=d][col=query]), direct from global channel-last
    bf16x8 qf[4];
#pragma unroll
    for (int tq = 0; tq < 4; ++tq) {
        int q = tq * 16 + lr;
        int pix = (wy * 8 + (q >> 3)) * IW + wx * 8 + (q & 7);
        qf[tq] = *(const bf16x8*)&qatt[((size_t)b * NPIX + pix) * CCH + head * HDIM + lg * 8];
    }

    // Bilinear sampling: K into A-fragments (regs), V into LDS
    float4 sbv = ((const float4*)sb)[(size_t)p * NWIN + win];
    bf16x8 kf[4];
#pragma unroll
    for (int mi = 0; mi < 4; ++mi) {
        int px = mi * 16 + lr;
        int dy = px >> 3, dx = px & 7;
        int yg = wy * 8 + dy, xg = wx * 8 + dx;
        float gx = -1.0f + xg * (2.0f / 127.0f) + ((float)dx - 3.5f) * (2.0f / 127.0f) * sbv.x + sbv.z;
        float gy = -1.0f + yg * (2.0f / 127.0f) + ((float)dy - 3.5f) * (2.0f / 127.0f) * sbv.y + sbv.w;
        float fx = (gx + 1.0f) * 0.5f * 127.0f;
        float fy = (gy + 1.0f) * 0.5f * 127.0f;
        float x0f = floorf(fx), y0f = floorf(fy);
        float wx1 = fx - x0f, wy1 = fy - y0f;
        int ix0 = (int)x0f, iy0 = (int)y0f;
        int ix1 = ix0 + 1, iy1 = iy0 + 1;
        float w00 = (1.0f - wx1) * (1.0f - wy1);
        float w10 = wx1 * (1.0f - wy1);
        float w01 = (1.0f - wx1) * wy1;
        float w11 = wx1 * wy1;
        bool vX0 = (ix0 >= 0) && (ix0 < IW), vX1 = (ix1 >= 0) && (ix1 < IW);
        bool vY0 = (iy0 >= 0) && (iy0 < IH), vY1 = (iy1 >= 0) && (iy1 < IH);
        if (!(vX0 && vY0)) w00 = 0.f;
        if (!(vX1 && vY0)) w10 = 0.f;
        if (!(vX0 && vY1)) w01 = 0.f;
        if (!(vX1 && vY1)) w11 = 0.f;
        int cx0 = min(max(ix0, 0), IW - 1), cx1 = min(max(ix1, 0), IW - 1);
        int cy0 = min(max(iy0, 0), IH - 1), cy1 = min(max(iy1, 0), IH - 1);
        size_t r00 = ((size_t)p * NPIX + cy0 * IW + cx0) * HDIM + lg * 8;
        size_t r10 = ((size_t)p * NPIX + cy0 * IW + cx1) * HDIM + lg * 8;
        size_t r01 = ((size_t)p * NPIX + cy1 * IW + cx0) * HDIM + lg * 8;
        size_t r11 = ((size_t)p * NPIX + cy1 * IW + cx1) * HDIM + lg * 8;
        u16x8 k00 = *(const u16x8*)&kb[r00], k10 = *(const u16x8*)&kb[r10];
        u16x8 k01 = *(const u16x8*)&kb[r01], k11 = *(const u16x8*)&kb[r11];
        u16x8 v00 = *(const u16x8*)&vb[r00], v10 = *(const u16x8*)&vb[r10];
        u16x8 v01 = *(const u16x8*)&vb[r01], v11 = *(const u16x8*)&vb[r11];
#pragma unroll
        for (int c = 0; c < 8; ++c) {
            float kvv = w00 * bf2f(k00[c]) + w10 * bf2f(k10[c]) +
                        w01 * bf2f(k01[c]) + w11 * bf2f(k11[c]);
            float vvv = w00 * bf2f(v00[c]) + w10 * bf2f(v10[c]) +
                        w01 * bf2f(v01[c]) + w11 * bf2f(v11[c]);
            kf[mi][c] = (short)f2bf(kvv);
            Vl[wv][px][lg * 8 + c] = f2bf(vvv);
        }
    }

    // S^T = K . Q^T : D[key=16tk+4lg+r][query=16tq+lr]
    f32x4 acc[4][4];
#pragma unroll
    for (int tk = 0; tk < 4; ++tk)
#pragma unroll
        for (int tq = 0; tq < 4; ++tq) acc[tk][tq] = (f32x4){0.f, 0.f, 0.f, 0.f};
#pragma unroll
    for (int tk = 0; tk < 4; ++tk)
#pragma unroll
        for (int tq = 0; tq < 4; ++tq)
            acc[tk][tq] = __builtin_amdgcn_mfma_f32_16x16x32_bf16(kf[tk], qf[tq], acc[tk][tq], 0, 0, 0);

    __syncthreads();   // rel_s visible

    // scale + rel bias + softmax over keys (per query col)
    const float scale = 0.17677669529663688f;
    int qh[4], qwv[4];
#pragma unroll
    for (int tq = 0; tq < 4; ++tq) { int q = tq * 16 + lr; qh[tq] = q >> 3; qwv[tq] = q & 7; }
    float mx[4] = {-1e30f, -1e30f, -1e30f, -1e30f};
#pragma unroll
    for (int tk = 0; tk < 4; ++tk)
#pragma unroll
        for (int r = 0; r < 4; ++r) {
            int key = tk * 16 + lg * 4 + r;
            int kh = key >> 3, kw = key & 7;
#pragma unroll
            for (int tq = 0; tq < 4; ++tq) {
                float v = acc[tk][tq][r] * scale + rel_s[(qh[tq] - kh + 7) * 15 + (qwv[tq] - kw + 7)];
                acc[tk][tq][r] = v;
                mx[tq] = fmaxf(mx[tq], v);
            }
        }
#pragma unroll
    for (int tq = 0; tq < 4; ++tq) {
        mx[tq] = fmaxf(mx[tq], __shfl_xor(mx[tq], 16));
        mx[tq] = fmaxf(mx[tq], __shfl_xor(mx[tq], 32));
    }
    float sm[4] = {0.f, 0.f, 0.f, 0.f};
#pragma unroll
    for (int tk = 0; tk < 4; ++tk)
#pragma unroll
        for (int tq = 0; tq < 4; ++tq)
#pragma unroll
            for (int r = 0; r < 4; ++r) {
                float e = __expf(acc[tk][tq][r] - mx[tq]);
                acc[tk][tq][r] = e;
                sm[tq] += e;
            }
    float inv[4];
#pragma unroll
    for (int tq = 0; tq < 4; ++tq) {
        float s = sm[tq];
        s += __shfl_xor(s, 16);
        s += __shfl_xor(s, 32);
        inv[tq] = 1.0f / s;
    }
    // write P (bf16) as [query][key]
#pragma unroll
    for (int tq = 0; tq < 4; ++tq)
#pragma unroll
        for (int tk = 0; tk < 4; ++tk) {
            u16x4 pk = { f2bf(acc[tk][tq][0] * inv[tq]), f2bf(acc[tk][tq][1] * inv[tq]),
                         f2bf(acc[tk][tq][2] * inv[tq]), f2bf(acc[tk][tq][3] * inv[tq]) };
            *(u16x4*)&Pl[wv][tq * 16 + lr][tk * 16 + lg * 4] = pk;
        }

    __syncthreads();   // P + V visible (wave-local, but barrier guarantees ordering)

    // O = P . V : D[q=16mq+4lg+r][d=16nd+lr]
    f32x4 o[4][2];
#pragma unroll
    for (int mq = 0; mq < 4; ++mq)
#pragma unroll
        for (int nd = 0; nd < 2; ++nd) o[mq][nd] = (f32x4){0.f, 0.f, 0.f, 0.f};
#pragma unroll
    for (int ks = 0; ks < 2; ++ks) {
        bf16x8 Af[4];
#pragma unroll
        for (int mq = 0; mq < 4; ++mq) {
            u16x4 lo = *(const u16x4*)&Pl[wv][mq * 16 + lr][ks * 32 + lg * 8];
            u16x4 hi = *(const u16x4*)&Pl[wv][mq * 16 + lr][ks * 32 + lg * 8 + 4];
#pragma unroll
            for (int c = 0; c < 4; ++c) { Af[mq][c] = (short)lo[c]; Af[mq][c + 4] = (short)hi[c]; }
        }
        bf16x8 Bf[2];
#pragma unroll
        for (int nd = 0; nd < 2; ++nd)
#pragma unroll
            for (int j = 0; j < 8; ++j)
                Bf[nd][j] = (short)Vl[wv][ks * 32 + lg * 8 + j][nd * 16 + lr];
#pragma unroll
        for (int mq = 0; mq < 4; ++mq)
#pragma unroll
            for (int nd = 0; nd < 2; ++nd)
                o[mq][nd] = __builtin_amdgcn_mfma_f32_16x16x32_bf16(Af[mq], Bf[nd], o[mq][nd], 0, 0, 0);
    }

    // write att (bf16, channel-last) into q buffer
#pragma unroll
    for (int mq = 0; mq < 4; ++mq)
#pragma unroll
        for (int nd = 0; nd < 2; ++nd)
#pragma unroll
            for (int r = 0; r < 4; ++r) {
                int q = mq * 16 + lg * 4 + r;
                int pix = (wy * 8 + (q >> 3)) * IW + wx * 8 + (q & 7);
                qatt[((size_t)b * NPIX + pix) * CCH + head * HDIM + nd * 16 + lr] = f2bf(o[mq][nd][r]);
            }
}

// ---------------------------------------------------------------------------
// K5: projection via bf16 MFMA: out = proj_w @ att + proj_b.
// ---------------------------------------------------------------------------
__global__ __launch_bounds__(256) void k5_mfma(const unsigned short* __restrict__ att,
                                               const float* __restrict__ proj_w,
                                               const float* __restrict__ proj_b,
                                               float* __restrict__ out) {
    constexpr int BN = 128, KC = 64, KCP = 72;
    __shared__ unsigned short Ws[CCH][KCP];
    __shared__ unsigned short Xt[BN][KCP];
    int px0 = blockIdx.x * BN;
    int b = blockIdx.y;
    int tid = threadIdx.x;
    int wv = tid >> 6, lane = tid & 63, lr = lane & 15, lg = lane >> 4;

    f32x4 acc[3][8];
#pragma unroll
    for (int i = 0; i < 3; ++i)
#pragma unroll
        for (int j = 0; j < 8; ++j) acc[i][j] = (f32x4){0.f, 0.f, 0.f, 0.f};

    int spx = tid & 127, skg = tid >> 7;

    for (int k0 = 0; k0 < CCH; k0 += KC) {
        for (int idx4 = tid; idx4 < CCH * KC / 4; idx4 += 256) {
            int o = idx4 >> 4, k4 = (idx4 & 15) * 4;
            float4 w4 = *(const float4*)&proj_w[(size_t)o * CCH + k0 + k4];
            u16x4 pk = { f2bf(w4.x), f2bf(w4.y), f2bf(w4.z), f2bf(w4.w) };
            *(u16x4*)&Ws[o][k4] = pk;
        }
        {
            const unsigned short* arow = &att[((size_t)b * NPIX + px0 + spx) * CCH + k0 + skg * 32];
#pragma unroll
            for (int j8 = 0; j8 < 4; ++j8)
                *(u16x8*)&Xt[spx][skg * 32 + j8 * 8] = *(const u16x8*)&arow[j8 * 8];
        }
        __syncthreads();
#pragma unroll
        for (int kk = 0; kk < KC; kk += 32) {
            bf16x8 af[3], bfr[8];
#pragma unroll
            for (int i = 0; i < 3; ++i)
                af[i] = *(const bf16x8*)&Ws[wv * 48 + i * 16 + lr][kk + lg * 8];
#pragma unroll
            for (int j = 0; j < 8; ++j)
                bfr[j] = *(const bf16x8*)&Xt[j * 16 + lr][kk + lg * 8];
#pragma unroll
            for (int i = 0; i < 3; ++i)
#pragma unroll
                for (int j = 0; j < 8; ++j)
                    acc[i][j] = __builtin_amdgcn_mfma_f32_16x16x32_bf16(af[i], bfr[j], acc[i][j], 0, 0, 0);
        }
        __syncthreads();
    }

#pragma unroll
    for (int i = 0; i < 3; ++i) {
        int och = wv * 48 + i * 16 + lg * 4;
#pragma unroll
        for (int r = 0; r < 4; ++r) {
            float bias = proj_b[och + r];
            size_t base = (size_t)(b * CCH + och + r) * NPIX + px0 + lr;
#pragma unroll
            for (int j = 0; j < 8; ++j)
                out[base + j * 16] = acc[i][j][r] + bias;
        }
    }
}

// ---------------------------------------------------------------------------
extern "C" void kernel_launch(void* const* d_in, const int* in_sizes, int n_in,
                              void* d_out, int out_size, void* d_ws, size_t ws_size,
                              hipStream_t stream) {
    const float* x = (const float*)d_in[0];
    const float* var = (const float*)d_in[1];
    const float* qkv_w = (const float*)d_in[2];
    const float* qkv_b = (const float*)d_in[3];
    const float* bias_w = (const float*)d_in[4];
    const float* bias_b = (const float*)d_in[5];
    const float* scale_w = (const float*)d_in[6];
    const float* scale_b = (const float*)d_in[7];
    const float* proj_w = (const float*)d_in[8];
    const float* proj_b = (const float*)d_in[9];
    const float* rel_table = (const float*)d_in[10];
    float* out = (float*)d_out;

    char* ws = (char*)d_ws;
    float* pooled = (float*)ws;                           // 393216 f32
    float* sb = (float*)(ws + 393216ull * 4);             // 49152 f32
    const size_t elemQ = (size_t)BB * CCH * NPIX;         // 25165824
    unsigned short* q = (unsigned short*)(ws + 1769472ull);
    unsigned short* k = q + elemQ;
    unsigned short* v = k + elemQ;

    size_t need = 1769472ull + 3ull * elemQ * 2;
    if (ws_size < need) return;

    k1_pool<<<dim3(BB * CCH), dim3(256), 0, stream>>>(x, var, pooled);
    k2_sb<<<dim3(BB * NWIN), dim3(64), 0, stream>>>(pooled, bias_w, bias_b, scale_w, scale_b, sb);
    k3_mfma<<<dim3(NPIX / 128, 3, BB), dim3(256), 0, stream>>>(x, qkv_w, qkv_b, q, k, v);
    k4_attn<<<dim3(NWIN / 4, NH, BB), dim3(256), 0, stream>>>(q, k, v, sb, rel_table);
    k5_mfma<<<dim3(NPIX / 128, BB), dim3(256), 0, stream>>>(q, proj_w, proj_b, out);
}

// Round 5
// 391.843 us; speedup vs baseline: 3.3440x; 1.1963x over previous
//
#include <hip/hip_runtime.h>
#include <hip/hip_bf16.h>
#include <math.h>

constexpr int BB = 8, CCH = 192, IH = 128, IW = 128;
constexpr int WSZ = 8;
constexpr int NWIN = 256;
constexpr int NH = 6, HDIM = 32;
constexpr int NPIX = IH * IW;
constexpr int TOPK = 13107;

typedef __attribute__((ext_vector_type(8))) short bf16x8;
typedef __attribute__((ext_vector_type(4))) float f32x4;
typedef __attribute__((ext_vector_type(4))) unsigned short u16x4;
typedef __attribute__((ext_vector_type(8))) unsigned short u16x8;

__device__ __forceinline__ unsigned short f2bf(float f) {
    __hip_bfloat16 h = __float2bfloat16(f);
    return __builtin_bit_cast(unsigned short, h);
}
__device__ __forceinline__ float bf2f(unsigned short u) {
    return __uint_as_float((unsigned)u << 16);
}
__device__ __forceinline__ unsigned monot(float f) {
    unsigned u = __float_as_uint(f);
    return (u & 0x80000000u) ? ~u : (u | 0x80000000u);
}

// ---------------------------------------------------------------------------
// K1: per (b,c) row: exact top-k threshold on var (stable ties like lax.top_k),
//     then masked 8x8 avg-pool + leaky_relu -> pooled (b, c, 16, 16).
//     Register-resident keys, per-wave histograms, wave-parallel suffix scan,
//     shfl-based pooling reduction (no atomics on the reduce).
// ---------------------------------------------------------------------------
__global__ __launch_bounds__(256) void k1_pool(const float* __restrict__ x,
                                               const float* __restrict__ var,
                                               float* __restrict__ pooled) {
    int row = blockIdx.x;
    const float4* vrow4 = (const float4*)(var + (size_t)row * NPIX);
    const float4* xrow4 = (const float4*)(x + (size_t)row * NPIX);
    int tid = threadIdx.x;
    int wv = tid >> 6, lane = tid & 63;

    __shared__ unsigned histA[4][257];
    __shared__ unsigned histB[4][257];
    __shared__ unsigned s_prefix, s_remaining;
    __shared__ unsigned eq_idx[64];
    __shared__ unsigned eq_cnt;
    __shared__ float wavepart[4][16][16];

    // load var, build monotonic keys (pixel = 4*tid + 1024*jj + c)
    unsigned m[64];
#pragma unroll
    for (int j = 0; j < 16; ++j) {
        float4 v4 = vrow4[tid + 256 * j];
        m[4 * j + 0] = monot(v4.x);
        m[4 * j + 1] = monot(v4.y);
        m[4 * j + 2] = monot(v4.z);
        m[4 * j + 3] = monot(v4.w);
    }
    for (int i = tid; i < 4 * 257; i += 256) ((unsigned*)histA)[i] = 0;
    if (tid == 0) eq_cnt = 0;
    __syncthreads();

    unsigned prefix = 0, remaining = TOPK;
    for (int pass = 0; pass < 4; ++pass) {
        int shift = 24 - 8 * pass;
        unsigned (*hcur)[257] = (pass & 1) ? histB : histA;
        unsigned (*hnext)[257] = (pass & 1) ? histA : histB;
#pragma unroll
        for (int j = 0; j < 64; ++j) {
            bool ok = (pass == 0) || ((m[j] >> (shift + 8)) == prefix);
            if (ok) atomicAdd(&hcur[wv][(m[j] >> shift) & 255u], 1u);
        }
        __syncthreads();
        if (wv == 0) {
            // lane owns buckets 4*lane .. 4*lane+3 (merged over 4 wave-hists)
            unsigned h[4];
#pragma unroll
            for (int i = 0; i < 4; ++i)
                h[i] = hcur[0][4 * lane + i] + hcur[1][4 * lane + i] +
                       hcur[2][4 * lane + i] + hcur[3][4 * lane + i];
            unsigned lsum = h[0] + h[1] + h[2] + h[3];
            unsigned s = lsum;
#pragma unroll
            for (int off = 1; off < 64; off <<= 1) {
                unsigned t = __shfl(s, lane + off);
                if (lane + off < 64) s += t;
            }
            unsigned snext = s - lsum;        // suffix sum starting at bucket 4*(lane+1)
            unsigned rem = remaining;
            int cand = -1;
            unsigned candRem = 0;
            unsigned suff = snext;
#pragma unroll
            for (int i = 3; i >= 0; --i) {    // suff becomes suffix incl. bucket 4*lane+i
                suff += h[i];
                if (cand < 0 && suff >= rem) {
                    cand = 4 * lane + i;
                    candRem = rem - (suff - h[i]);
                }
            }
            unsigned long long bal = __ballot(cand >= 0);
            int src = 63 - __builtin_clzll(bal);   // largest lane with a crossing
            int bs = __shfl(cand, src);
            unsigned crem = __shfl(candRem, src);
            if (lane == 0) {
                s_prefix = (prefix << 8) | (unsigned)bs;
                s_remaining = crem;
            }
        } else if (wv == 1) {
            for (int i = lane; i < 4 * 257; i += 64) ((unsigned*)hnext)[i] = 0;
        }
        __syncthreads();
        prefix = s_prefix;
        remaining = s_remaining;
    }
    unsigned thr = prefix;
    unsigned need_eq = remaining;

    // collect tie indices (stable, ascending)
#pragma unroll
    for (int j = 0; j < 64; ++j) {
        if (m[j] == thr) {
            unsigned pos = atomicAdd(&eq_cnt, 1u);
            if (pos < 64) eq_idx[pos] = (unsigned)(4 * tid + 1024 * (j >> 2) + (j & 3));
        }
    }
    __syncthreads();
    int ecnt = (int)min(eq_cnt, 64u);
    if (tid == 0) {
        for (int a = 1; a < ecnt; ++a) {
            unsigned key = eq_idx[a]; int q = a - 1;
            while (q >= 0 && eq_idx[q] > key) { eq_idx[q + 1] = eq_idx[q]; --q; }
            eq_idx[q + 1] = key;
        }
    }
    __syncthreads();

    // pooling: chunk j of thread t covers window (wy=j, wx=(t>>1)&15)
    int w = (tid >> 1) & 15;
#pragma unroll
    for (int j = 0; j < 16; ++j) {
        float4 x4 = xrow4[tid + 256 * j];
        float xv[4] = {x4.x, x4.y, x4.z, x4.w};
        float part = 0.f;
#pragma unroll
        for (int c = 0; c < 4; ++c) {
            unsigned mm = m[4 * j + c];
            float mult;
            if (mm > thr) mult = 1.0f;
            else if (mm < thr) mult = 0.6f;
            else {
                int i = 4 * tid + 1024 * j + c;
                unsigned rank = 0;
                for (int e = 0; e < ecnt; ++e) if (eq_idx[e] < (unsigned)i) ++rank;
                mult = (rank < need_eq) ? 1.0f : 0.6f;
            }
            part += xv[c] * mult;
        }
        part += __shfl_xor(part, 1);
        part += __shfl_xor(part, 32);
        if ((lane & 1) == 0 && lane < 32) wavepart[wv][j][lane >> 1] = part;
    }
    __syncthreads();
    {
        int j = tid >> 4, ww = tid & 15;
        float s = wavepart[0][j][ww] + wavepart[1][j][ww] +
                  wavepart[2][j][ww] + wavepart[3][j][ww];
        s *= (1.0f / 64.0f);
        float pv = s > 0.f ? s : 0.01f * s;
        pooled[(size_t)row * NWIN + tid] = pv;
    }
}

// ---------------------------------------------------------------------------
// K2: per (b, window): dots with bias_w/scale_w -> sb[p][win] = {sx,sy,bx/16,by/16}
// ---------------------------------------------------------------------------
__global__ __launch_bounds__(64) void k2_sb(const float* __restrict__ pooled,
                                            const float* __restrict__ bias_w,
                                            const float* __restrict__ bias_b,
                                            const float* __restrict__ scale_w,
                                            const float* __restrict__ scale_b,
                                            float* __restrict__ sb) {
    int blk = blockIdx.x;
    int b = blk / NWIN, w = blk % NWIN;
    int tid = threadIdx.x;
    __shared__ float pcol[CCH];
    __shared__ float res[24];
    for (int c = tid; c < CCH; c += 64) pcol[c] = pooled[(size_t)(b * CCH + c) * NWIN + w];
    __syncthreads();
    if (tid < 24) {
        bool isScale = tid >= 12;
        int o = isScale ? tid - 12 : tid;
        const float* Wt = isScale ? scale_w : bias_w;
        float acc = 0.f;
        for (int c = 0; c < CCH; ++c) acc += Wt[o * CCH + c] * pcol[c];
        acc += (isScale ? scale_b[o] : bias_b[o]);
        if (!isScale) acc *= (1.0f / 16.0f);
        res[tid] = acc;
    }
    __syncthreads();
    if (tid < NH) {
        int p = b * NH + tid;
        float4 v;
        v.x = res[12 + 2 * tid];
        v.y = res[12 + 2 * tid + 1];
        v.z = res[2 * tid];
        v.w = res[2 * tid + 1];
        ((float4*)sb)[(size_t)p * NWIN + w] = v;
    }
}

// ---------------------------------------------------------------------------
// K3: qkv 1x1 conv via bf16 MFMA, channel-last outputs:
//     q: (b, px, 192)   k/v: (b*NH+head, px, 32)
// ---------------------------------------------------------------------------
__global__ __launch_bounds__(256) void k3_mfma(const float* __restrict__ x,
                                               const float* __restrict__ qkv_w,
                                               const float* __restrict__ qkv_b,
                                               unsigned short* __restrict__ qb,
                                               unsigned short* __restrict__ kb,
                                               unsigned short* __restrict__ vb) {
    constexpr int BN = 128, KC = 64, KCP = 72;
    __shared__ unsigned short Ws[CCH][KCP];   // [o][k]
    __shared__ unsigned short Xt[BN][KCP];    // [px][k]
    int px0 = blockIdx.x * BN;
    int t = blockIdx.y, b = blockIdx.z;
    int o0 = t * CCH;
    int tid = threadIdx.x;
    int wv = tid >> 6, lane = tid & 63, lr = lane & 15, lg = lane >> 4;

    f32x4 acc[3][8];
#pragma unroll
    for (int i = 0; i < 3; ++i)
#pragma unroll
        for (int j = 0; j < 8; ++j) acc[i][j] = (f32x4){0.f, 0.f, 0.f, 0.f};

    int spx = tid & 127, skg = tid >> 7;

    for (int k0 = 0; k0 < CCH; k0 += KC) {
        for (int idx4 = tid; idx4 < CCH * KC / 4; idx4 += 256) {
            int o = idx4 >> 4, k4 = (idx4 & 15) * 4;
            float4 w4 = *(const float4*)&qkv_w[(size_t)(o0 + o) * CCH + k0 + k4];
            u16x4 pk = { f2bf(w4.x), f2bf(w4.y), f2bf(w4.z), f2bf(w4.w) };
            *(u16x4*)&Ws[o][k4] = pk;
        }
        {
            const float* xcol = &x[(size_t)(b * CCH + k0 + skg * 32) * NPIX + px0 + spx];
#pragma unroll
            for (int j8 = 0; j8 < 4; ++j8) {
                u16x8 pk;
#pragma unroll
                for (int j = 0; j < 8; ++j) pk[j] = f2bf(xcol[(size_t)(j8 * 8 + j) * NPIX]);
                *(u16x8*)&Xt[spx][skg * 32 + j8 * 8] = pk;
            }
        }
        __syncthreads();
#pragma unroll
        for (int kk = 0; kk < KC; kk += 32) {
            bf16x8 af[3], bfr[8];
#pragma unroll
            for (int i = 0; i < 3; ++i)
                af[i] = *(const bf16x8*)&Ws[wv * 48 + i * 16 + lr][kk + lg * 8];
#pragma unroll
            for (int j = 0; j < 8; ++j)
                bfr[j] = *(const bf16x8*)&Xt[j * 16 + lr][kk + lg * 8];
#pragma unroll
            for (int i = 0; i < 3; ++i)
#pragma unroll
                for (int j = 0; j < 8; ++j)
                    acc[i][j] = __builtin_amdgcn_mfma_f32_16x16x32_bf16(af[i], bfr[j], acc[i][j], 0, 0, 0);
        }
        __syncthreads();
    }

#pragma unroll
    for (int i = 0; i < 3; ++i) {
        int och = wv * 48 + i * 16 + lg * 4;
        float b0 = qkv_b[o0 + och], b1 = qkv_b[o0 + och + 1];
        float b2 = qkv_b[o0 + och + 2], b3 = qkv_b[o0 + och + 3];
#pragma unroll
        for (int j = 0; j < 8; ++j) {
            int px = px0 + lr + j * 16;
            u16x4 pk = { f2bf(acc[i][j][0] + b0), f2bf(acc[i][j][1] + b1),
                         f2bf(acc[i][j][2] + b2), f2bf(acc[i][j][3] + b3) };
            if (t == 0) {
                *(u16x4*)&qb[((size_t)b * NPIX + px) * CCH + och] = pk;
            } else {
                int head = och >> 5, d = och & 31;
                unsigned short* dst = (t == 1) ? kb : vb;
                *(u16x4*)&dst[(((size_t)(b * NH + head)) * NPIX + px) * HDIM + d] = pk;
            }
        }
    }
}

// ---------------------------------------------------------------------------
// K4: wave-per-window MFMA attention. S^T = K_samp . Q^T, softmax in-register,
//     PV via MFMA with P,V in LDS. Writes att (bf16, channel-last) into qb.
// ---------------------------------------------------------------------------
__global__ __launch_bounds__(256) void k4_attn(unsigned short* __restrict__ qatt,
                                               const unsigned short* __restrict__ kb,
                                               const unsigned short* __restrict__ vb,
                                               const float* __restrict__ sb,
                                               const float* __restrict__ rel_table) {
    int tid = threadIdx.x;
    int wv = tid >> 6, lane = tid & 63, lr = lane & 15, lg = lane >> 4;
    int head = blockIdx.y, b = blockIdx.z;
    int win = blockIdx.x * 4 + wv;
    int wy = win >> 4, wx = win & 15;
    int p = b * NH + head;

    __shared__ float rel_s[225];
    __shared__ unsigned short Vl[4][64][33];   // [wave][key px][d]
    __shared__ unsigned short Pl[4][64][68];   // [wave][query][key]

    if (tid < 225) rel_s[tid] = rel_table[tid * NH + head];

    bf16x8 qf[4];
#pragma unroll
    for (int tq = 0; tq < 4; ++tq) {
        int q = tq * 16 + lr;
        int pix = (wy * 8 + (q >> 3)) * IW + wx * 8 + (q & 7);
        qf[tq] = *(const bf16x8*)&qatt[((size_t)b * NPIX + pix) * CCH + head * HDIM + lg * 8];
    }

    float4 sbv = ((const float4*)sb)[(size_t)p * NWIN + win];
    bf16x8 kf[4];
#pragma unroll
    for (int mi = 0; mi < 4; ++mi) {
        int px = mi * 16 + lr;
        int dy = px >> 3, dx = px & 7;
        int yg = wy * 8 + dy, xg = wx * 8 + dx;
        float gx = -1.0f + xg * (2.0f / 127.0f) + ((float)dx - 3.5f) * (2.0f / 127.0f) * sbv.x + sbv.z;
        float gy = -1.0f + yg * (2.0f / 127.0f) + ((float)dy - 3.5f) * (2.0f / 127.0f) * sbv.y + sbv.w;
        float fx = (gx + 1.0f) * 0.5f * 127.0f;
        float fy = (gy + 1.0f) * 0.5f * 127.0f;
        float x0f = floorf(fx), y0f = floorf(fy);
        float wx1 = fx - x0f, wy1 = fy - y0f;
        int ix0 = (int)x0f, iy0 = (int)y0f;
        int ix1 = ix0 + 1, iy1 = iy0 + 1;
        float w00 = (1.0f - wx1) * (1.0f - wy1);
        float w10 = wx1 * (1.0f - wy1);
        float w01 = (1.0f - wx1) * wy1;
        float w11 = wx1 * wy1;
        bool vX0 = (ix0 >= 0) && (ix0 < IW), vX1 = (ix1 >= 0) && (ix1 < IW);
        bool vY0 = (iy0 >= 0) && (iy0 < IH), vY1 = (iy1 >= 0) && (iy1 < IH);
        if (!(vX0 && vY0)) w00 = 0.f;
        if (!(vX1 && vY0)) w10 = 0.f;
        if (!(vX0 && vY1)) w01 = 0.f;
        if (!(vX1 && vY1)) w11 = 0.f;
        int cx0 = min(max(ix0, 0), IW - 1), cx1 = min(max(ix1, 0), IW - 1);
        int cy0 = min(max(iy0, 0), IH - 1), cy1 = min(max(iy1, 0), IH - 1);
        size_t r00 = ((size_t)p * NPIX + cy0 * IW + cx0) * HDIM + lg * 8;
        size_t r10 = ((size_t)p * NPIX + cy0 * IW + cx1) * HDIM + lg * 8;
        size_t r01 = ((size_t)p * NPIX + cy1 * IW + cx0) * HDIM + lg * 8;
        size_t r11 = ((size_t)p * NPIX + cy1 * IW + cx1) * HDIM + lg * 8;
        u16x8 k00 = *(const u16x8*)&kb[r00], k10 = *(const u16x8*)&kb[r10];
        u16x8 k01 = *(const u16x8*)&kb[r01], k11 = *(const u16x8*)&kb[r11];
        u16x8 v00 = *(const u16x8*)&vb[r00], v10 = *(const u16x8*)&vb[r10];
        u16x8 v01 = *(const u16x8*)&vb[r01], v11 = *(const u16x8*)&vb[r11];
#pragma unroll
        for (int c = 0; c < 8; ++c) {
            float kvv = w00 * bf2f(k00[c]) + w10 * bf2f(k10[c]) +
                        w01 * bf2f(k01[c]) + w11 * bf2f(k11[c]);
            float vvv = w00 * bf2f(v00[c]) + w10 * bf2f(v10[c]) +
                        w01 * bf2f(v01[c]) + w11 * bf2f(v11[c]);
            kf[mi][c] = (short)f2bf(kvv);
            Vl[wv][px][lg * 8 + c] = f2bf(vvv);
        }
    }

    f32x4 acc[4][4];
#pragma unroll
    for (int tk = 0; tk < 4; ++tk)
#pragma unroll
        for (int tq = 0; tq < 4; ++tq) acc[tk][tq] = (f32x4){0.f, 0.f, 0.f, 0.f};
#pragma unroll
    for (int tk = 0; tk < 4; ++tk)
#pragma unroll
        for (int tq = 0; tq < 4; ++tq)
            acc[tk][tq] = __builtin_amdgcn_mfma_f32_16x16x32_bf16(kf[tk], qf[tq], acc[tk][tq], 0, 0, 0);

    __syncthreads();

    const float scale = 0.17677669529663688f;
    int qh[4], qwv[4];
#pragma unroll
    for (int tq = 0; tq < 4; ++tq) { int q = tq * 16 + lr; qh[tq] = q >> 3; qwv[tq] = q & 7; }
    float mx[4] = {-1e30f, -1e30f, -1e30f, -1e30f};
#pragma unroll
    for (int tk = 0; tk < 4; ++tk)
#pragma unroll
        for (int r = 0; r < 4; ++r) {
            int key = tk * 16 + lg * 4 + r;
            int kh = key >> 3, kw = key & 7;
#pragma unroll
            for (int tq = 0; tq < 4; ++tq) {
                float v = acc[tk][tq][r] * scale + rel_s[(qh[tq] - kh + 7) * 15 + (qwv[tq] - kw + 7)];
                acc[tk][tq][r] = v;
                mx[tq] = fmaxf(mx[tq], v);
            }
        }
#pragma unroll
    for (int tq = 0; tq < 4; ++tq) {
        mx[tq] = fmaxf(mx[tq], __shfl_xor(mx[tq], 16));
        mx[tq] = fmaxf(mx[tq], __shfl_xor(mx[tq], 32));
    }
    float sm[4] = {0.f, 0.f, 0.f, 0.f};
#pragma unroll
    for (int tk = 0; tk < 4; ++tk)
#pragma unroll
        for (int tq = 0; tq < 4; ++tq)
#pragma unroll
            for (int r = 0; r < 4; ++r) {
                float e = __expf(acc[tk][tq][r] - mx[tq]);
                acc[tk][tq][r] = e;
                sm[tq] += e;
            }
    float inv[4];
#pragma unroll
    for (int tq = 0; tq < 4; ++tq) {
        float s = sm[tq];
        s += __shfl_xor(s, 16);
        s += __shfl_xor(s, 32);
        inv[tq] = 1.0f / s;
    }
#pragma unroll
    for (int tq = 0; tq < 4; ++tq)
#pragma unroll
        for (int tk = 0; tk < 4; ++tk) {
            u16x4 pk = { f2bf(acc[tk][tq][0] * inv[tq]), f2bf(acc[tk][tq][1] * inv[tq]),
                         f2bf(acc[tk][tq][2] * inv[tq]), f2bf(acc[tk][tq][3] * inv[tq]) };
            *(u16x4*)&Pl[wv][tq * 16 + lr][tk * 16 + lg * 4] = pk;
        }

    __syncthreads();

    f32x4 o[4][2];
#pragma unroll
    for (int mq = 0; mq < 4; ++mq)
#pragma unroll
        for (int nd = 0; nd < 2; ++nd) o[mq][nd] = (f32x4){0.f, 0.f, 0.f, 0.f};
#pragma unroll
    for (int ks = 0; ks < 2; ++ks) {
        bf16x8 Af[4];
#pragma unroll
        for (int mq = 0; mq < 4; ++mq) {
            u16x4 lo = *(const u16x4*)&Pl[wv][mq * 16 + lr][ks * 32 + lg * 8];
            u16x4 hi = *(const u16x4*)&Pl[wv][mq * 16 + lr][ks * 32 + lg * 8 + 4];
#pragma unroll
            for (int c = 0; c < 4; ++c) { Af[mq][c] = (short)lo[c]; Af[mq][c + 4] = (short)hi[c]; }
        }
        bf16x8 Bf[2];
#pragma unroll
        for (int nd = 0; nd < 2; ++nd)
#pragma unroll
            for (int j = 0; j < 8; ++j)
                Bf[nd][j] = (short)Vl[wv][ks * 32 + lg * 8 + j][nd * 16 + lr];
#pragma unroll
        for (int mq = 0; mq < 4; ++mq)
#pragma unroll
            for (int nd = 0; nd < 2; ++nd)
                o[mq][nd] = __builtin_amdgcn_mfma_f32_16x16x32_bf16(Af[mq], Bf[nd], o[mq][nd], 0, 0, 0);
    }

#pragma unroll
    for (int mq = 0; mq < 4; ++mq)
#pragma unroll
        for (int nd = 0; nd < 2; ++nd)
#pragma unroll
            for (int r = 0; r < 4; ++r) {
                int q = mq * 16 + lg * 4 + r;
                int pix = (wy * 8 + (q >> 3)) * IW + wx * 8 + (q & 7);
                qatt[((size_t)b * NPIX + pix) * CCH + head * HDIM + nd * 16 + lr] = f2bf(o[mq][nd][r]);
            }
}

// ---------------------------------------------------------------------------
// K5: projection via bf16 MFMA: out = proj_w @ att + proj_b.
// ---------------------------------------------------------------------------
__global__ __launch_bounds__(256) void k5_mfma(const unsigned short* __restrict__ att,
                                               const float* __restrict__ proj_w,
                                               const float* __restrict__ proj_b,
                                               float* __restrict__ out) {
    constexpr int BN = 128, KC = 64, KCP = 72;
    __shared__ unsigned short Ws[CCH][KCP];
    __shared__ unsigned short Xt[BN][KCP];
    int px0 = blockIdx.x * BN;
    int b = blockIdx.y;
    int tid = threadIdx.x;
    int wv = tid >> 6, lane = tid & 63, lr = lane & 15, lg = lane >> 4;

    f32x4 acc[3][8];
#pragma unroll
    for (int i = 0; i < 3; ++i)
#pragma unroll
        for (int j = 0; j < 8; ++j) acc[i][j] = (f32x4){0.f, 0.f, 0.f, 0.f};

    int spx = tid & 127, skg = tid >> 7;

    for (int k0 = 0; k0 < CCH; k0 += KC) {
        for (int idx4 = tid; idx4 < CCH * KC / 4; idx4 += 256) {
            int o = idx4 >> 4, k4 = (idx4 & 15) * 4;
            float4 w4 = *(const float4*)&proj_w[(size_t)o * CCH + k0 + k4];
            u16x4 pk = { f2bf(w4.x), f2bf(w4.y), f2bf(w4.z), f2bf(w4.w) };
            *(u16x4*)&Ws[o][k4] = pk;
        }
        {
            const unsigned short* arow = &att[((size_t)b * NPIX + px0 + spx) * CCH + k0 + skg * 32];
#pragma unroll
            for (int j8 = 0; j8 < 4; ++j8)
                *(u16x8*)&Xt[spx][skg * 32 + j8 * 8] = *(const u16x8*)&arow[j8 * 8];
        }
        __syncthreads();
#pragma unroll
        for (int kk = 0; kk < KC; kk += 32) {
            bf16x8 af[3], bfr[8];
#pragma unroll
            for (int i = 0; i < 3; ++i)
                af[i] = *(const bf16x8*)&Ws[wv * 48 + i * 16 + lr][kk + lg * 8];
#pragma unroll
            for (int j = 0; j < 8; ++j)
                bfr[j] = *(const bf16x8*)&Xt[j * 16 + lr][kk + lg * 8];
#pragma unroll
            for (int i = 0; i < 3; ++i)
#pragma unroll
                for (int j = 0; j < 8; ++j)
                    acc[i][j] = __builtin_amdgcn_mfma_f32_16x16x32_bf16(af[i], bfr[j], acc[i][j], 0, 0, 0);
        }
        __syncthreads();
    }

#pragma unroll
    for (int i = 0; i < 3; ++i) {
        int och = wv * 48 + i * 16 + lg * 4;
#pragma unroll
        for (int r = 0; r < 4; ++r) {
            float bias = proj_b[och + r];
            size_t base = (size_t)(b * CCH + och + r) * NPIX + px0 + lr;
#pragma unroll
            for (int j = 0; j < 8; ++j)
                out[base + j * 16] = acc[i][j][r] + bias;
        }
    }
}

// ---------------------------------------------------------------------------
extern "C" void kernel_launch(void* const* d_in, const int* in_sizes, int n_in,
                              void* d_out, int out_size, void* d_ws, size_t ws_size,
                              hipStream_t stream) {
    const float* x = (const float*)d_in[0];
    const float* var = (const float*)d_in[1];
    const float* qkv_w = (const float*)d_in[2];
    const float* qkv_b = (const float*)d_in[3];
    const float* bias_w = (const float*)d_in[4];
    const float* bias_b = (const float*)d_in[5];
    const float* scale_w = (const float*)d_in[6];
    const float* scale_b = (const float*)d_in[7];
    const float* proj_w = (const float*)d_in[8];
    const float* proj_b = (const float*)d_in[9];
    const float* rel_table = (const float*)d_in[10];
    float* out = (float*)d_out;

    char* ws = (char*)d_ws;
    float* pooled = (float*)ws;                           // 393216 f32
    float* sb = (float*)(ws + 393216ull * 4);             // 49152 f32
    const size_t elemQ = (size_t)BB * CCH * NPIX;         // 25165824
    unsigned short* q = (unsigned short*)(ws + 1769472ull);
    unsigned short* k = q + elemQ;
    unsigned short* v = k + elemQ;

    size_t need = 1769472ull + 3ull * elemQ * 2;
    if (ws_size < need) return;

    k1_pool<<<dim3(BB * CCH), dim3(256), 0, stream>>>(x, var, pooled);
    k2_sb<<<dim3(BB * NWIN), dim3(64), 0, stream>>>(pooled, bias_w, bias_b, scale_w, scale_b, sb);
    k3_mfma<<<dim3(NPIX / 128, 3, BB), dim3(256), 0, stream>>>(x, qkv_w, qkv_b, q, k, v);
    k4_attn<<<dim3(NWIN / 4, NH, BB), dim3(256), 0, stream>>>(q, k, v, sb, rel_table);
    k5_mfma<<<dim3(NPIX / 128, BB), dim3(256), 0, stream>>>(q, proj_w, proj_b, out);
}